// Round 1
// baseline (507.100 us; speedup 1.0000x reference)
//
#include <hip/hip_runtime.h>
#include <math.h>

#define BATCH 32768

__device__ __forceinline__ float shflx(float v, int m) {
  return __shfl_xor(v, m, 64);
}

// ---------------- gates ----------------
// Amp index k (10 bits): wire w <-> bit (9-w). lane = k>>4 (bits 9..4), reg = k&15 (bits 3..0).
// wires 0..5 -> lane bits 5..0 ; wires 6..9 -> reg bits 3..0.

template<int BB>  // Rot on reg-bit BB (wire 9-BB... i.e. wire w=9-BB? no: wire w -> BB=9-w)
__device__ __forceinline__ void rot_reg(float ar[16], float ai[16], const float* __restrict__ u) {
  const float u00r=u[0],u00i=u[1],u01r=u[2],u01i=u[3];
  const float u10r=u[4],u10i=u[5],u11r=u[6],u11i=u[7];
#pragma unroll
  for (int r0 = 0; r0 < 16; ++r0) {
    if ((r0 >> BB) & 1) continue;
    const int r1 = r0 | (1 << BB);
    const float a0r=ar[r0], a0i=ai[r0], a1r=ar[r1], a1i=ai[r1];
    ar[r0] = fmaf(u00r,a0r, fmaf(-u00i,a0i, fmaf(u01r,a1r, -u01i*a1i)));
    ai[r0] = fmaf(u00r,a0i, fmaf( u00i,a0r, fmaf(u01r,a1i,  u01i*a1r)));
    ar[r1] = fmaf(u10r,a0r, fmaf(-u10i,a0i, fmaf(u11r,a1r, -u11i*a1i)));
    ai[r1] = fmaf(u10r,a0i, fmaf( u10i,a0r, fmaf(u11r,a1i,  u11i*a1r)));
  }
}

template<int LB>  // Rot on lane-bit LB
__device__ __forceinline__ void rot_lane(float ar[16], float ai[16], const float* __restrict__ u, int lane) {
  const bool hi = (lane >> LB) & 1;
  const float var_ = hi ? u[6] : u[0];   // coeff for own amp
  const float vai  = hi ? u[7] : u[1];
  const float vbr  = hi ? u[4] : u[2];   // coeff for partner amp
  const float vbi  = hi ? u[5] : u[3];
#pragma unroll
  for (int r = 0; r < 16; ++r) {
    const float pr_ = shflx(ar[r], 1 << LB);
    const float pi_ = shflx(ai[r], 1 << LB);
    const float nr = fmaf(var_,ar[r], fmaf(-vai,ai[r], fmaf(vbr,pr_, -vbi*pi_)));
    const float ni = fmaf(var_,ai[r], fmaf( vai,ar[r], fmaf(vbr,pi_,  vbi*pr_)));
    ar[r] = nr; ai[r] = ni;
  }
}

template<int CB, int TB>  // control reg-bit, target reg-bit: compile-time register swap
__device__ __forceinline__ void cnot_rr(float ar[16], float ai[16]) {
#pragma unroll
  for (int r = 0; r < 16; ++r) {
    if (((r >> CB) & 1) && !((r >> TB) & 1)) {
      const int r2 = r | (1 << TB);
      float t;
      t = ar[r]; ar[r] = ar[r2]; ar[r2] = t;
      t = ai[r]; ai[r] = ai[r2]; ai[r2] = t;
    }
  }
}

template<int CL, int TB>  // control lane-bit, target reg-bit: predicated swap
__device__ __forceinline__ void cnot_lr(float ar[16], float ai[16], int lane) {
  const bool c = (lane >> CL) & 1;
#pragma unroll
  for (int r = 0; r < 16; ++r) {
    if (!((r >> TB) & 1)) {
      const int r2 = r | (1 << TB);
      const float a0 = ar[r], a1 = ar[r2];
      ar[r]  = c ? a1 : a0;  ar[r2] = c ? a0 : a1;
      const float b0 = ai[r], b1 = ai[r2];
      ai[r]  = c ? b1 : b0;  ai[r2] = c ? b0 : b1;
    }
  }
}

template<int CB, int TL>  // control reg-bit, target lane-bit: shuffle only control=1 regs
__device__ __forceinline__ void cnot_rl(float ar[16], float ai[16]) {
#pragma unroll
  for (int r = 0; r < 16; ++r) {
    if ((r >> CB) & 1) {
      ar[r] = shflx(ar[r], 1 << TL);
      ai[r] = shflx(ai[r], 1 << TL);
    }
  }
}

template<int CL, int TL>  // control lane-bit, target lane-bit
__device__ __forceinline__ void cnot_ll(float ar[16], float ai[16], int lane) {
  const bool c = (lane >> CL) & 1;
#pragma unroll
  for (int r = 0; r < 16; ++r) {
    const float pr_ = shflx(ar[r], 1 << TL);
    const float pi_ = shflx(ai[r], 1 << TL);
    ar[r] = c ? pr_ : ar[r];
    ai[r] = c ? pi_ : ai[r];
  }
}

template<int W>
__device__ __forceinline__ void do_rot(float ar[16], float ai[16], const float* __restrict__ u, int lane) {
  if constexpr (W <= 5) rot_lane<5 - W>(ar, ai, u, lane);
  else                  rot_reg<9 - W>(ar, ai, u);
}

template<int C, int T>
__device__ __forceinline__ void do_cnot(float ar[16], float ai[16], int lane) {
  if constexpr (C <= 5 && T <= 5)      cnot_ll<5 - C, 5 - T>(ar, ai, lane);
  else if constexpr (C <= 5)           cnot_lr<5 - C, 9 - T>(ar, ai, lane);
  else if constexpr (T <= 5)           cnot_rl<9 - C, 5 - T>(ar, ai);
  else                                 cnot_rr<9 - C, 9 - T>(ar, ai);
}

// ---------------- main kernel: one wave per sample ----------------
__global__ __launch_bounds__(256) void qnn_kernel(
    const float* __restrict__ x, const float* __restrict__ Wpre,
    const float* __restrict__ bpre, const float* __restrict__ qw,
    const float* __restrict__ Wpost, const float* __restrict__ bpost,
    float* __restrict__ out)
{
  __shared__ float Ush[4 * 10 * 8];

  const int tid = threadIdx.x;
  // 40 Rot matrices are batch-uniform: compute once per block into LDS.
  if (tid < 40) {
    const float phi = qw[tid * 3 + 0];
    const float th  = qw[tid * 3 + 1];
    const float om  = qw[tid * 3 + 2];
    const float c  = cosf(0.5f * th), s = sinf(0.5f * th);
    const float aa = 0.5f * (phi + om), bb = 0.5f * (phi - om);
    const float ca = cosf(aa), sa = sinf(aa);
    const float cb = cosf(bb), sb = sinf(bb);
    float* U = &Ush[tid * 8];
    U[0] =  ca * c;  U[1] = -sa * c;   // u00
    U[2] = -cb * s;  U[3] = -sb * s;   // u01
    U[4] =  cb * s;  U[5] = -sb * s;   // u10
    U[6] =  ca * c;  U[7] =  sa * c;   // u11
  }
  __syncthreads();

  const int lane = tid & 63;
  const int b = blockIdx.x * 4 + (tid >> 6);

  // ---- pre-net: angles = tanh(x @ Wpre^T + bpre), lane-parallel over features ----
  const float* xrow = x + (size_t)b * 128;
  const float x0 = xrow[lane];
  const float x1 = xrow[lane + 64];
  float cw[10], sw[10];
#pragma unroll
  for (int w = 0; w < 10; ++w) {
    float p = fmaf(x0, Wpre[w * 128 + lane], x1 * Wpre[w * 128 + 64 + lane]);
    p += shflx(p, 1);  p += shflx(p, 2);  p += shflx(p, 4);
    p += shflx(p, 8);  p += shflx(p, 16); p += shflx(p, 32);
    const float ang = tanhf(p + bpre[w]);
    const float h = 0.5f * ang;
    cw[w] = __cosf(h);
    sw[w] = __sinf(h);
  }

  // ---- embedding: direct tensor-product construction ----
  // psi[k] = (prod_w m_w) * (-i)^popcount(k)
  float ml = 1.f;
#pragma unroll
  for (int w = 0; w < 6; ++w)
    ml *= ((lane >> (5 - w)) & 1) ? sw[w] : cw[w];
  const int pm = __popc(lane) & 3;
  const float phr  = (pm == 0) ? ml : ((pm == 2) ? -ml : 0.f);
  const float phiv = (pm == 1) ? -ml : ((pm == 3) ? ml : 0.f);

  float ar[16], ai[16];
#pragma unroll
  for (int r = 0; r < 16; ++r) {
    const float mr = ((r & 8) ? sw[6] : cw[6]) * ((r & 4) ? sw[7] : cw[7]) *
                     ((r & 2) ? sw[8] : cw[8]) * ((r & 1) ? sw[9] : cw[9]);
    const int pr = __popc(r) & 3;
    const float br = (pr == 0) ? phr  : (pr == 1) ? phiv : (pr == 2) ? -phr  : -phiv;
    const float bi = (pr == 0) ? phiv : (pr == 1) ? -phr : (pr == 2) ? -phiv :  phr;
    ar[r] = mr * br;
    ai[r] = mr * bi;
  }

#define UP(L, W) (Ush + ((L) * 10 + (W)) * 8)

  // ---- layer 0 (r=1) ----
  do_rot<0>(ar, ai, UP(0,0), lane); do_rot<1>(ar, ai, UP(0,1), lane);
  do_rot<2>(ar, ai, UP(0,2), lane); do_rot<3>(ar, ai, UP(0,3), lane);
  do_rot<4>(ar, ai, UP(0,4), lane); do_rot<5>(ar, ai, UP(0,5), lane);
  do_rot<6>(ar, ai, UP(0,6), lane); do_rot<7>(ar, ai, UP(0,7), lane);
  do_rot<8>(ar, ai, UP(0,8), lane); do_rot<9>(ar, ai, UP(0,9), lane);
  do_cnot<0,1>(ar, ai, lane); do_cnot<1,2>(ar, ai, lane);
  do_cnot<2,3>(ar, ai, lane); do_cnot<3,4>(ar, ai, lane);
  do_cnot<4,5>(ar, ai, lane); do_cnot<5,6>(ar, ai, lane);
  do_cnot<6,7>(ar, ai, lane); do_cnot<7,8>(ar, ai, lane);
  do_cnot<8,9>(ar, ai, lane); do_cnot<9,0>(ar, ai, lane);

  // ---- layer 1 (r=2) ----
  do_rot<0>(ar, ai, UP(1,0), lane); do_rot<1>(ar, ai, UP(1,1), lane);
  do_rot<2>(ar, ai, UP(1,2), lane); do_rot<3>(ar, ai, UP(1,3), lane);
  do_rot<4>(ar, ai, UP(1,4), lane); do_rot<5>(ar, ai, UP(1,5), lane);
  do_rot<6>(ar, ai, UP(1,6), lane); do_rot<7>(ar, ai, UP(1,7), lane);
  do_rot<8>(ar, ai, UP(1,8), lane); do_rot<9>(ar, ai, UP(1,9), lane);
  do_cnot<0,2>(ar, ai, lane); do_cnot<1,3>(ar, ai, lane);
  do_cnot<2,4>(ar, ai, lane); do_cnot<3,5>(ar, ai, lane);
  do_cnot<4,6>(ar, ai, lane); do_cnot<5,7>(ar, ai, lane);
  do_cnot<6,8>(ar, ai, lane); do_cnot<7,9>(ar, ai, lane);
  do_cnot<8,0>(ar, ai, lane); do_cnot<9,1>(ar, ai, lane);

  // ---- layer 2 (r=3) ----
  do_rot<0>(ar, ai, UP(2,0), lane); do_rot<1>(ar, ai, UP(2,1), lane);
  do_rot<2>(ar, ai, UP(2,2), lane); do_rot<3>(ar, ai, UP(2,3), lane);
  do_rot<4>(ar, ai, UP(2,4), lane); do_rot<5>(ar, ai, UP(2,5), lane);
  do_rot<6>(ar, ai, UP(2,6), lane); do_rot<7>(ar, ai, UP(2,7), lane);
  do_rot<8>(ar, ai, UP(2,8), lane); do_rot<9>(ar, ai, UP(2,9), lane);
  do_cnot<0,3>(ar, ai, lane); do_cnot<1,4>(ar, ai, lane);
  do_cnot<2,5>(ar, ai, lane); do_cnot<3,6>(ar, ai, lane);
  do_cnot<4,7>(ar, ai, lane); do_cnot<5,8>(ar, ai, lane);
  do_cnot<6,9>(ar, ai, lane); do_cnot<7,0>(ar, ai, lane);
  do_cnot<8,1>(ar, ai, lane); do_cnot<9,2>(ar, ai, lane);

  // ---- layer 3 (r=4) ----
  do_rot<0>(ar, ai, UP(3,0), lane); do_rot<1>(ar, ai, UP(3,1), lane);
  do_rot<2>(ar, ai, UP(3,2), lane); do_rot<3>(ar, ai, UP(3,3), lane);
  do_rot<4>(ar, ai, UP(3,4), lane); do_rot<5>(ar, ai, UP(3,5), lane);
  do_rot<6>(ar, ai, UP(3,6), lane); do_rot<7>(ar, ai, UP(3,7), lane);
  do_rot<8>(ar, ai, UP(3,8), lane); do_rot<9>(ar, ai, UP(3,9), lane);
  do_cnot<0,4>(ar, ai, lane); do_cnot<1,5>(ar, ai, lane);
  do_cnot<2,6>(ar, ai, lane); do_cnot<3,7>(ar, ai, lane);
  do_cnot<4,8>(ar, ai, lane); do_cnot<5,9>(ar, ai, lane);
  do_cnot<6,0>(ar, ai, lane); do_cnot<7,1>(ar, ai, lane);
  do_cnot<8,2>(ar, ai, lane); do_cnot<9,3>(ar, ai, lane);

#undef UP

  // ---- epilogue: acc = sum_k prob_k * g(k), g = sum_i Wpost_i * (1 - 2*bit_i(k)) ----
  float Wp[10];
#pragma unroll
  for (int i = 0; i < 10; ++i) Wp[i] = Wpost[i];

  float gL = 0.f;
#pragma unroll
  for (int w = 0; w < 6; ++w)
    gL += ((lane >> (5 - w)) & 1) ? -Wp[w] : Wp[w];

  float acc = 0.f;
#pragma unroll
  for (int r = 0; r < 16; ++r) {
    const float g = gL + ((r & 8) ? -Wp[6] : Wp[6]) + ((r & 4) ? -Wp[7] : Wp[7])
                       + ((r & 2) ? -Wp[8] : Wp[8]) + ((r & 1) ? -Wp[9] : Wp[9]);
    const float p = fmaf(ar[r], ar[r], ai[r] * ai[r]);
    acc = fmaf(p, g, acc);
  }
  acc += shflx(acc, 1);  acc += shflx(acc, 2);  acc += shflx(acc, 4);
  acc += shflx(acc, 8);  acc += shflx(acc, 16); acc += shflx(acc, 32);

  if (lane == 0) {
    const float z = acc + bpost[0];
    out[b] = 1.f / (1.f + expf(-z));
  }
}

extern "C" void kernel_launch(void* const* d_in, const int* in_sizes, int n_in,
                              void* d_out, int out_size, void* d_ws, size_t ws_size,
                              hipStream_t stream) {
  const float* x     = (const float*)d_in[0];
  const float* Wpre  = (const float*)d_in[1];
  const float* bpre  = (const float*)d_in[2];
  const float* qw    = (const float*)d_in[3];
  const float* Wpost = (const float*)d_in[4];
  const float* bpost = (const float*)d_in[5];
  float* out = (float*)d_out;

  (void)in_sizes; (void)n_in; (void)out_size; (void)d_ws; (void)ws_size;

  qnn_kernel<<<BATCH / 4, 256, 0, stream>>>(x, Wpre, bpre, qw, Wpost, bpost, out);
}

// Round 2
// 366.632 us; speedup vs baseline: 1.3831x; 1.3831x over previous
//
#include <hip/hip_runtime.h>
#include <math.h>

#define BATCH 32768

typedef float v2f __attribute__((ext_vector_type(2)));

// ---------------------------------------------------------------------------
// Compile-time circuit derivation (lazy CNOT tracking over GF(2)).
// Physical index p (10 bits): lane = p>>4 (bits 9..4), reg = p&15 (bits 3..0).
// Wire w <-> bit (9-w). Stored S[p] = psi[A p]; CNOT(c,t) updates A for free:
//   row[bt] ^= row[bc]  (A rows, for hi-bit selection parity)
//   col[bc] ^= col[bt]  (A^-1 cols, for partner xor mask)
// Rot on wire w at layer l uses prt = col[9-w], sel = row[9-w] at that time.
// Final measurement signs use final rows.
// ---------------------------------------------------------------------------
struct GateC { unsigned prt, sel; };
struct CircuitT { GateC g[4][10]; unsigned srow[10]; };

constexpr CircuitT make_circuit() {
  CircuitT C{};
  unsigned row[10], col[10];
  for (int b = 0; b < 10; ++b) { row[b] = 1u << b; col[b] = 1u << b; }
  for (int l = 0; l < 4; ++l) {
    for (int w = 0; w < 10; ++w) {
      C.g[l][w].prt = col[9 - w];
      C.g[l][w].sel = row[9 - w];
    }
    const int r = (l % 9) + 1;
    for (int w = 0; w < 10; ++w) {
      const int c = w, t = (w + r) % 10;
      const int bc = 9 - c, bt = 9 - t;
      row[bt] ^= row[bc];
      col[bc] ^= col[bt];
    }
  }
  for (int i = 0; i < 10; ++i) C.srow[i] = row[9 - i];
  return C;
}
constexpr CircuitT CIRC = make_circuit();

// xor-shuffle: masks 1..31 -> single ds_swizzle (imm pattern); bit5 -> ds_bpermute
template<int PL>
__device__ __forceinline__ float shufl(float v, int bpa) {
  if constexpr ((PL & 32) == 0) {
    return __int_as_float(__builtin_amdgcn_ds_swizzle(__float_as_int(v), 0x1F | (PL << 10)));
  } else {
    return __int_as_float(__builtin_amdgcn_ds_bpermute(bpa, __float_as_int(v)));
  }
}

__device__ __forceinline__ float shflx(float v, int m) {
  return __shfl_xor(v, m, 64);
}

// Generalized Rot gate. Coefficients (global-phase-reduced so u00 is real):
//   u00 = A (real), u01 = B, u10 = C, u11 = D   (B,C,D complex)
// hi(p) = parity(p & sel); partner(p) = p ^ prt.
// hi=0: new = A*a + B*part ; hi=1: new = D*a + C*part
template<int L, int W>
__device__ __forceinline__ void gate(v2f a[16], const float* __restrict__ Ug, int lane) {
  constexpr unsigned PRT = CIRC.g[L][W].prt;
  constexpr unsigned SEL = CIRC.g[L][W].sel;
  constexpr int PLm = (int)(PRT >> 4);
  constexpr int PRm = (int)(PRT & 15u);
  constexpr int SLm = (int)(SEL >> 4);
  constexpr int SRm = (int)(SEL & 15u);

  const float4 u0 = *(const float4*)(Ug);
  const float4 u1 = *(const float4*)(Ug + 4);
  const float A  = u0.x, Br = u0.y, Bi = u0.z, Cr = u0.w;
  const float Ci = u1.x, Dr = u1.y, Di = u1.z;

  // coefficient sets for reg-parity cr=0 (set0) and cr=1 (set1)
  float O0r, O0i, P0r, P0i, O1r, O1i, P1r, P1i;
  if constexpr (SLm != 0) {
    const bool hl = (__popc(lane & SLm) & 1) != 0;
    O0r = hl ? Dr : A;   O0i = hl ? Di : 0.f;
    P0r = hl ? Cr : Br;  P0i = hl ? Ci : Bi;
    O1r = hl ? A  : Dr;  O1i = hl ? 0.f : Di;
    P1r = hl ? Br : Cr;  P1i = hl ? Bi : Ci;
  } else {
    O0r = A;  O0i = 0.f; P0r = Br; P0i = Bi;
    O1r = Dr; O1i = Di;  P1r = Cr; P1i = Ci;
  }

  int bpa = 0;
  if constexpr ((PLm & 32) != 0) bpa = ((lane ^ PLm) << 2);

  if constexpr (PLm == 0) {
    // pure register-pair gate
    constexpr int LB = PRm & (-PRm);
#pragma unroll
    for (int r0 = 0; r0 < 16; ++r0) {
      if (r0 & LB) continue;
      const int r1 = r0 ^ PRm;
      const int c0 = __popc(r0 & SRm) & 1;
      const int c1 = __popc(r1 & SRm) & 1;
      const v2f a0 = a[r0], a1 = a[r1];
      const v2f j0 = {-a0.y, a0.x};
      const v2f j1 = {-a1.y, a1.x};
      const float oAr = c0 ? O1r : O0r, oAi = c0 ? O1i : O0i;
      const float pAr = c0 ? P1r : P0r, pAi = c0 ? P1i : P0i;
      const float oBr = c1 ? O1r : O0r, oBi = c1 ? O1i : O0i;
      const float pBr = c1 ? P1r : P0r, pBi = c1 ? P1i : P0i;
      a[r0] = a0 * oAr + j0 * oAi + a1 * pAr + j1 * pAi;
      a[r1] = a1 * oBr + j1 * oBi + a0 * pBr + j0 * pBi;
    }
  } else if constexpr (PRm == 0) {
    // lane-crossing, same reg
#pragma unroll
    for (int r = 0; r < 16; ++r) {
      const int cr = __popc(r & SRm) & 1;
      const float oR = cr ? O1r : O0r, oI = cr ? O1i : O0i;
      const float pR = cr ? P1r : P0r, pI = cr ? P1i : P0i;
      const v2f own = a[r];
      const float px = shufl<PLm>(own.x, bpa);
      const float py = shufl<PLm>(own.y, bpa);
      const v2f p  = {px, py};
      const v2f jo = {-own.y, own.x};
      const v2f jp = {-py, px};
      a[r] = own * oR + jo * oI + p * pR + jp * pI;
    }
  } else {
    // lane-crossing with reg swap: partner of (lane,r0) is (lane^PL, r1)
    constexpr int LB = PRm & (-PRm);
#pragma unroll
    for (int r0 = 0; r0 < 16; ++r0) {
      if (r0 & LB) continue;
      const int r1 = r0 ^ PRm;
      const int c0 = __popc(r0 & SRm) & 1;
      const int c1 = __popc(r1 & SRm) & 1;
      const v2f a0 = a[r0], a1 = a[r1];
      const float p0x = shufl<PLm>(a1.x, bpa);
      const float p0y = shufl<PLm>(a1.y, bpa);
      const float p1x = shufl<PLm>(a0.x, bpa);
      const float p1y = shufl<PLm>(a0.y, bpa);
      const v2f p0 = {p0x, p0y}, jp0 = {-p0y, p0x};
      const v2f p1 = {p1x, p1y}, jp1 = {-p1y, p1x};
      const v2f j0 = {-a0.y, a0.x}, j1 = {-a1.y, a1.x};
      const float oAr = c0 ? O1r : O0r, oAi = c0 ? O1i : O0i;
      const float pAr = c0 ? P1r : P0r, pAi = c0 ? P1i : P0i;
      const float oBr = c1 ? O1r : O0r, oBi = c1 ? O1i : O0i;
      const float pBr = c1 ? P1r : P0r, pBi = c1 ? P1i : P0i;
      a[r0] = a0 * oAr + j0 * oAi + p0 * pAr + jp0 * pAi;
      a[r1] = a1 * oBr + j1 * oBi + p1 * pBr + jp1 * pBi;
    }
  }
}

template<int L, int W>
__device__ __forceinline__ void layer_from(v2f a[16], const float* __restrict__ Ush, int lane) {
  if constexpr (W < 10) {
    gate<L, W>(a, Ush + (L * 10 + W) * 8, lane);
    layer_from<L, W + 1>(a, Ush, lane);
  }
}

// ---------------- main kernel: one wave per sample ----------------
__global__ __launch_bounds__(256, 4) void qnn_kernel(
    const float* __restrict__ x, const float* __restrict__ Wpre,
    const float* __restrict__ bpre, const float* __restrict__ qw,
    const float* __restrict__ Wpost, const float* __restrict__ bpost,
    float* __restrict__ out)
{
  __shared__ float Ush[4 * 10 * 8];

  const int tid = threadIdx.x;
  // 40 Rot matrices are batch-uniform; phase-reduced layout {A,Br,Bi,Cr,Ci,Dr,Di,0}
  if (tid < 40) {
    const float phi = qw[tid * 3 + 0];
    const float th  = qw[tid * 3 + 1];
    const float om  = qw[tid * 3 + 2];
    const float c = cosf(0.5f * th), s = sinf(0.5f * th);
    float* U = &Ush[tid * 8];
    U[0] = c;                      // A  = u00 (real after phase reduction)
    U[1] = -cosf(phi) * s;         // Br
    U[2] = -sinf(phi) * s;         // Bi
    U[3] =  cosf(om) * s;          // Cr
    U[4] =  sinf(om) * s;          // Ci
    U[5] =  cosf(phi + om) * c;    // Dr
    U[6] =  sinf(phi + om) * c;    // Di
    U[7] = 0.f;
  }
  __syncthreads();

  const int lane = tid & 63;
  const int b = blockIdx.x * 4 + (tid >> 6);

  // ---- pre-net: angles = tanh(x @ Wpre^T + bpre), lane-parallel over features ----
  const float* xrow = x + (size_t)b * 128;
  const float x0 = xrow[lane];
  const float x1 = xrow[lane + 64];
  float cw[10], sw[10];
#pragma unroll
  for (int w = 0; w < 10; ++w) {
    float p = fmaf(x0, Wpre[w * 128 + lane], x1 * Wpre[w * 128 + 64 + lane]);
    p += shflx(p, 1);  p += shflx(p, 2);  p += shflx(p, 4);
    p += shflx(p, 8);  p += shflx(p, 16); p += shflx(p, 32);
    // fast tanh: 1 - 2/(e^{2x}+1)
    const float e = __expf(2.f * (p + bpre[w]));
    const float ang = 1.f - 2.f * __builtin_amdgcn_rcpf(e + 1.f);
    const float h = 0.5f * ang;
    cw[w] = __cosf(h);
    sw[w] = __sinf(h);
  }

  // ---- embedding: psi[k] = (prod_w m_w) * (-i)^popcount(k)  (A = I here) ----
  float ml = 1.f;
#pragma unroll
  for (int w = 0; w < 6; ++w)
    ml *= ((lane >> (5 - w)) & 1) ? sw[w] : cw[w];
  const int pm = __popc(lane) & 3;
  const float phr  = (pm == 0) ? ml : ((pm == 2) ? -ml : 0.f);
  const float phiv = (pm == 1) ? -ml : ((pm == 3) ? ml : 0.f);
  const v2f ph[4] = { {phr, phiv}, {phiv, -phr}, {-phr, -phiv}, {-phiv, phr} };

  const float mh[4]  = { cw[6]*cw[7], cw[6]*sw[7], sw[6]*cw[7], sw[6]*sw[7] };
  const float mlo[4] = { cw[8]*cw[9], cw[8]*sw[9], sw[8]*cw[9], sw[8]*sw[9] };

  v2f a[16];
#pragma unroll
  for (int r = 0; r < 16; ++r) {
    const float mr = mh[r >> 2] * mlo[r & 3];
    a[r] = ph[__popc(r) & 3] * mr;
  }

  // ---- 40 generalized Rot gates (all CNOTs folded into masks) ----
  layer_from<0, 0>(a, Ush, lane);
  layer_from<1, 0>(a, Ush, lane);
  layer_from<2, 0>(a, Ush, lane);
  layer_from<3, 0>(a, Ush, lane);

  // ---- epilogue: acc = sum_p |a|^2 * g(p); g = sum_i W_i * sign(parity(p & srow_i)) ----
  float Wl[10];
#pragma unroll
  for (int i = 0; i < 10; ++i) {
    const int sl = (int)(CIRC.srow[i] >> 4);
    const int par = __popc(lane & sl) & 1;
    const float wv = Wpost[i];
    Wl[i] = par ? -wv : wv;
  }

  v2f acc2 = {0.f, 0.f};
#pragma unroll
  for (int r = 0; r < 16; ++r) {
    float g = 0.f;
#pragma unroll
    for (int i = 0; i < 10; ++i) {
      g += (__popc(r & (int)(CIRC.srow[i] & 15u)) & 1) ? -Wl[i] : Wl[i];
    }
    acc2 += (a[r] * a[r]) * g;
  }
  float acc = acc2.x + acc2.y;
  acc += shflx(acc, 1);  acc += shflx(acc, 2);  acc += shflx(acc, 4);
  acc += shflx(acc, 8);  acc += shflx(acc, 16); acc += shflx(acc, 32);

  if (lane == 0) {
    const float z = acc + bpost[0];
    out[b] = __builtin_amdgcn_rcpf(1.f + __expf(-z));
  }
}

extern "C" void kernel_launch(void* const* d_in, const int* in_sizes, int n_in,
                              void* d_out, int out_size, void* d_ws, size_t ws_size,
                              hipStream_t stream) {
  const float* x     = (const float*)d_in[0];
  const float* Wpre  = (const float*)d_in[1];
  const float* bpre  = (const float*)d_in[2];
  const float* qw    = (const float*)d_in[3];
  const float* Wpost = (const float*)d_in[4];
  const float* bpost = (const float*)d_in[5];
  float* out = (float*)d_out;

  (void)in_sizes; (void)n_in; (void)out_size; (void)d_ws; (void)ws_size;

  qnn_kernel<<<BATCH / 4, 256, 0, stream>>>(x, Wpre, bpre, qw, Wpost, bpost, out);
}

// Round 3
// 322.483 us; speedup vs baseline: 1.5725x; 1.1369x over previous
//
#include <hip/hip_runtime.h>
#include <math.h>

#define BATCH 32768

typedef float v2f __attribute__((ext_vector_type(2)));

// ---------------------------------------------------------------------------
// Compile-time circuit derivation (lazy CNOT tracking over GF(2)).
// Physical index p (10 bits): lane = p>>4 (bits 9..4), reg slot = p&15.
// Pack: reg bit0 = position inside v2f; pair index j = slot>>1 (3 bits).
// ---------------------------------------------------------------------------
struct GateC { unsigned prt, sel; };
struct CircuitT { GateC g[4][10]; unsigned srow[10]; };

constexpr CircuitT make_circuit() {
  CircuitT C{};
  unsigned row[10], col[10];
  for (int b = 0; b < 10; ++b) { row[b] = 1u << b; col[b] = 1u << b; }
  for (int l = 0; l < 4; ++l) {
    for (int w = 0; w < 10; ++w) {
      C.g[l][w].prt = col[9 - w];
      C.g[l][w].sel = row[9 - w];
    }
    const int r = (l % 9) + 1;
    for (int w = 0; w < 10; ++w) {
      const int c = w, t = (w + r) % 10;
      const int bc = 9 - c, bt = 9 - t;
      row[bt] ^= row[bc];
      col[bc] ^= col[bt];
    }
  }
  for (int i = 0; i < 10; ++i) C.srow[i] = row[9 - i];
  return C;
}
constexpr CircuitT CIRC = make_circuit();

constexpr unsigned long long make_sbits() {
  unsigned long long b = 0;
  for (int l = 0; l < 4; ++l)
    for (int w = 0; w < 10; ++w)
      if (CIRC.g[l][w].sel & 1u) b |= 1ull << (l * 10 + w);
  return b;
}
constexpr unsigned long long SBITS = make_sbits();

// ---------------- packed fp32 primitives (plain VOP3P, no modifiers) --------
__device__ __forceinline__ v2f pk_mul(v2f a, v2f b) {
  v2f d; asm("v_pk_mul_f32 %0, %1, %2" : "=v"(d) : "v"(a), "v"(b)); return d;
}
__device__ __forceinline__ v2f pk_fma(v2f a, v2f b, v2f c) {
  v2f d; asm("v_pk_fma_f32 %0, %1, %2, %3" : "=v"(d) : "v"(a), "v"(b), "v"(c)); return d;
}

// xor-shuffle: masks 1..31 -> single ds_swizzle; mask with bit5 -> ds_bpermute
template<int PL>
__device__ __forceinline__ float shufl(float v, int bpa) {
  if constexpr ((PL & 32) == 0) {
    return __int_as_float(__builtin_amdgcn_ds_swizzle(__float_as_int(v), 0x1F | (PL << 10)));
  } else {
    return __int_as_float(__builtin_amdgcn_ds_bpermute(bpa, __float_as_int(v)));
  }
}
__device__ __forceinline__ float shflx(float v, int m) { return __shfl_xor(v, m, 64); }

// one slot-pair complex update: new = O*own + P*partner (coeff vectors per slot)
__device__ __forceinline__ void cupdate(const v2f Rj, const v2f Ij, const v2f pR, const v2f pI,
                                        const v2f Or_, const v2f Oi_, const v2f mOi,
                                        const v2f Pr_, const v2f Pi_, const v2f mPi,
                                        v2f &nR, v2f &nI) {
  nR = pk_mul(Rj, Or_);
  nR = pk_fma(Ij, mOi, nR);
  nR = pk_fma(pR, Pr_, nR);
  nR = pk_fma(pI, mPi, nR);
  nI = pk_mul(Ij, Or_);
  nI = pk_fma(Rj, Oi_, nI);
  nI = pk_fma(pI, Pr_, nI);
  nI = pk_fma(pR, Pi_, nI);
}

template<int L, int W>
__device__ __forceinline__ void gate(v2f R[8], v2f I[8], const float* __restrict__ Ush, int lane) {
  constexpr unsigned PRT = CIRC.g[L][W].prt;
  constexpr unsigned SEL = CIRC.g[L][W].sel;
  constexpr int PLm = (int)(PRT >> 4), PRm = (int)(PRT & 15u);
  constexpr int SLm = (int)(SEL >> 4), SRm = (int)(SEL & 15u);
  constexpr int PRh = PRm >> 1, PSW = PRm & 1;
  constexpr int SRh = SRm >> 1;

  int hl = 0;
  if constexpr (SLm != 0) hl = __popc(lane & SLm) & 1;

  const float* gb = Ush + (L * 10 + W) * 32;
  const v2f* cA = (const v2f*)(gb + (hl << 4));
  v2f vOr[2], vOi[2], vmOi[2], vPr[2], vPi[2], vmPi[2];
  vOr[0] = cA[0]; vOi[0] = cA[1]; vmOi[0] = cA[2];
  vPr[0] = cA[3]; vPi[0] = cA[4]; vmPi[0] = cA[5];
  if constexpr (SRh != 0) {
    const v2f* cB = (const v2f*)(gb + ((hl ^ 1) << 4));
    vOr[1] = cB[0]; vOi[1] = cB[1]; vmOi[1] = cB[2];
    vPr[1] = cB[3]; vPi[1] = cB[4]; vmPi[1] = cB[5];
  } else {
    vOr[1] = vOr[0]; vOi[1] = vOi[0]; vmOi[1] = vmOi[0];
    vPr[1] = vPr[0]; vPi[1] = vPi[0]; vmPi[1] = vmPi[0];
  }

  int bpa = 0;
  if constexpr ((PLm & 32) != 0) bpa = (lane ^ PLm) << 2;

#pragma unroll
  for (int j = 0; j < 8; ++j) {
    const int jp = j ^ PRh;
    if (jp < j) continue;          // couple {j, jp} processed together
    const int q0 = __builtin_popcount(j & SRh) & 1;
    const int q1 = __builtin_popcount(jp & SRh) & 1;
    v2f pR0, pI0, pR1, pI1;
    if constexpr (PLm == 0) {
      if constexpr (PSW) {
        pR0 = v2f{R[jp].y, R[jp].x}; pI0 = v2f{I[jp].y, I[jp].x};
        pR1 = v2f{R[j].y,  R[j].x};  pI1 = v2f{I[j].y,  I[j].x};
      } else {
        pR0 = R[jp]; pI0 = I[jp]; pR1 = R[j]; pI1 = I[j];
      }
    } else {
      const float rx = shufl<PLm>(R[jp].x, bpa), ry = shufl<PLm>(R[jp].y, bpa);
      const float ix = shufl<PLm>(I[jp].x, bpa), iy = shufl<PLm>(I[jp].y, bpa);
      pR0 = PSW ? v2f{ry, rx} : v2f{rx, ry};
      pI0 = PSW ? v2f{iy, ix} : v2f{ix, iy};
      if (jp != j) {
        const float rx1 = shufl<PLm>(R[j].x, bpa), ry1 = shufl<PLm>(R[j].y, bpa);
        const float ix1 = shufl<PLm>(I[j].x, bpa), iy1 = shufl<PLm>(I[j].y, bpa);
        pR1 = PSW ? v2f{ry1, rx1} : v2f{rx1, ry1};
        pI1 = PSW ? v2f{iy1, ix1} : v2f{ix1, iy1};
      }
    }
    v2f nR0, nI0, nR1, nI1;
    cupdate(R[j], I[j], pR0, pI0, vOr[q0], vOi[q0], vmOi[q0], vPr[q0], vPi[q0], vmPi[q0], nR0, nI0);
    if (jp != j)
      cupdate(R[jp], I[jp], pR1, pI1, vOr[q1], vOi[q1], vmOi[q1], vPr[q1], vPi[q1], vmPi[q1], nR1, nI1);
    R[j] = nR0; I[j] = nI0;
    if (jp != j) { R[jp] = nR1; I[jp] = nI1; }
  }
}

template<int L, int W>
__device__ __forceinline__ void layer_from(v2f R[8], v2f I[8], const float* __restrict__ Ush, int lane) {
  if constexpr (W < 10) {
    gate<L, W>(R, I, Ush, lane);
    layer_from<L, W + 1>(R, I, Ush, lane);
  }
}

// ---------------- main kernel: one wave per sample ----------------
__global__ __launch_bounds__(256, 4) void qnn_kernel(
    const float* __restrict__ x, const float* __restrict__ Wpre,
    const float* __restrict__ bpre, const float* __restrict__ qw,
    const float* __restrict__ Wpost, const float* __restrict__ bpost,
    float* __restrict__ out)
{
  __shared__ __align__(16) float Ush[40 * 32];

  const int tid = threadIdx.x;
  // Per gate: 2 variants x 6 coefficient v2f, precomputed (batch-uniform).
  // Class-c coeffs: O(c) = c ? (Dr,Di) : (A,0); P(c) = c ? (Cr,Ci) : (Br,Bi).
  // Variant v, slot t holds coeff class (v ^ (t & s)), s = SRm&1.
  if (tid < 40) {
    const float phi = qw[tid * 3 + 0];
    const float th  = qw[tid * 3 + 1];
    const float om  = qw[tid * 3 + 2];
    const float c = cosf(0.5f * th), s_ = sinf(0.5f * th);
    const float A  = c;
    const float Br = -cosf(phi) * s_, Bi = -sinf(phi) * s_;
    const float Cr =  cosf(om)  * s_, Ci =  sinf(om)  * s_;
    const float Dr =  cosf(phi + om) * c, Di = sinf(phi + om) * c;
    const int s = (int)((SBITS >> tid) & 1ull);
    float* gbv = &Ush[tid * 32];
#pragma unroll
    for (int v = 0; v < 2; ++v) {
      const int c0 = v, c1 = v ^ s;
      float* p = gbv + v * 16;
      const float Or0 = c0 ? Dr : A,   Or1 = c1 ? Dr : A;
      const float Oi0 = c0 ? Di : 0.f, Oi1 = c1 ? Di : 0.f;
      const float Pr0 = c0 ? Cr : Br,  Pr1 = c1 ? Cr : Br;
      const float Pi0 = c0 ? Ci : Bi,  Pi1 = c1 ? Ci : Bi;
      p[0] = Or0;  p[1] = Or1;  p[2] = Oi0;  p[3] = Oi1;
      p[4] = -Oi0; p[5] = -Oi1; p[6] = Pr0;  p[7] = Pr1;
      p[8] = Pi0;  p[9] = Pi1;  p[10] = -Pi0; p[11] = -Pi1;
    }
  }
  __syncthreads();

  const int lane = tid & 63;
  const int b = blockIdx.x * 4 + (tid >> 6);

  // ---- pre-net: angles = tanh(x @ Wpre^T + bpre) ----
  const float* xrow = x + (size_t)b * 128;
  const float x0 = xrow[lane];
  const float x1 = xrow[lane + 64];
  float cw[10], sw[10];
#pragma unroll
  for (int w = 0; w < 10; ++w) {
    float p = fmaf(x0, Wpre[w * 128 + lane], x1 * Wpre[w * 128 + 64 + lane]);
    p += shflx(p, 1);  p += shflx(p, 2);  p += shflx(p, 4);
    p += shflx(p, 8);  p += shflx(p, 16); p += shflx(p, 32);
    const float e = __expf(2.f * (p + bpre[w]));
    const float ang = 1.f - 2.f * __builtin_amdgcn_rcpf(e + 1.f);
    const float h = 0.5f * ang;
    cw[w] = __cosf(h);
    sw[w] = __sinf(h);
  }

  // ---- embedding: psi[k] = (prod_w m_w) * (-i)^popcount(k), SoA packed ----
  float ml = 1.f;
#pragma unroll
  for (int w = 0; w < 6; ++w)
    ml *= ((lane >> (5 - w)) & 1) ? sw[w] : cw[w];
  const int pm = __popc(lane) & 3;
  const float phr  = (pm == 0) ? ml : ((pm == 2) ? -ml : 0.f);
  const float phiv = (pm == 1) ? -ml : ((pm == 3) ? ml : 0.f);
  const v2f ph2[4] = { {phr, phiv}, {phiv, -phr}, {-phr, -phiv}, {-phiv, phr} };

  const float mh4[4]  = { cw[6]*cw[7], cw[6]*sw[7], sw[6]*cw[7], sw[6]*sw[7] };
  const float mlo4[4] = { cw[8]*cw[9], cw[8]*sw[9], sw[8]*cw[9], sw[8]*sw[9] };

  v2f R[8], I[8];
#pragma unroll
  for (int j = 0; j < 8; ++j) {
    const int r0 = 2 * j, r1 = 2 * j + 1;
    const float m0 = mh4[r0 >> 2] * mlo4[r0 & 3];
    const float m1 = mh4[r1 >> 2] * mlo4[r1 & 3];
    const int p0 = __popc(r0) & 3, p1 = __popc(r1) & 3;
    R[j] = v2f{ph2[p0].x * m0, ph2[p1].x * m1};
    I[j] = v2f{ph2[p0].y * m0, ph2[p1].y * m1};
  }

  // ---- 40 generalized Rot gates (all CNOTs folded into masks) ----
  layer_from<0, 0>(R, I, Ush, lane);
  layer_from<1, 0>(R, I, Ush, lane);
  layer_from<2, 0>(R, I, Ush, lane);
  layer_from<3, 0>(R, I, Ush, lane);

  // ---- epilogue: acc = sum_p |a|^2 * g(p); g = sum_i W_i * sign(parity(p & srow_i)) ----
  float Wl[10];
#pragma unroll
  for (int i = 0; i < 10; ++i) {
    const int sl = (int)(CIRC.srow[i] >> 4);
    const int par = __popc(lane & sl) & 1;
    const float wv = Wpost[i];
    Wl[i] = par ? -wv : wv;
  }

  float acc = 0.f;
#pragma unroll
  for (int r = 0; r < 16; ++r) {
    float g = 0.f;
#pragma unroll
    for (int i = 0; i < 10; ++i) {
      g += (__popc(r & (int)(CIRC.srow[i] & 15u)) & 1) ? -Wl[i] : Wl[i];
    }
    const float rr = (r & 1) ? R[r >> 1].y : R[r >> 1].x;
    const float ii = (r & 1) ? I[r >> 1].y : I[r >> 1].x;
    const float p = fmaf(rr, rr, ii * ii);
    acc = fmaf(p, g, acc);
  }
  acc += shflx(acc, 1);  acc += shflx(acc, 2);  acc += shflx(acc, 4);
  acc += shflx(acc, 8);  acc += shflx(acc, 16); acc += shflx(acc, 32);

  if (lane == 0) {
    const float z = acc + bpost[0];
    out[b] = __builtin_amdgcn_rcpf(1.f + __expf(-z));
  }
}

extern "C" void kernel_launch(void* const* d_in, const int* in_sizes, int n_in,
                              void* d_out, int out_size, void* d_ws, size_t ws_size,
                              hipStream_t stream) {
  const float* x     = (const float*)d_in[0];
  const float* Wpre  = (const float*)d_in[1];
  const float* bpre  = (const float*)d_in[2];
  const float* qw    = (const float*)d_in[3];
  const float* Wpost = (const float*)d_in[4];
  const float* bpost = (const float*)d_in[5];
  float* out = (float*)d_out;

  (void)in_sizes; (void)n_in; (void)out_size; (void)d_ws; (void)ws_size;

  qnn_kernel<<<BATCH / 4, 256, 0, stream>>>(x, Wpre, bpre, qw, Wpost, bpost, out);
}

// Round 5
// 317.650 us; speedup vs baseline: 1.5964x; 1.0152x over previous
//
#include <hip/hip_runtime.h>
#include <math.h>

#define BATCH 32768

typedef float v2f __attribute__((ext_vector_type(2)));
typedef float v4f __attribute__((ext_vector_type(4)));

#if defined(__has_builtin)
#if __has_builtin(__builtin_amdgcn_permlane32_swap) && __has_builtin(__builtin_amdgcn_permlane16_swap)
#define USE_PERMLANE 1
#else
#define USE_PERMLANE 0
#endif
#else
#define USE_PERMLANE 0
#endif

// ---------------------------------------------------------------------------
// Compile-time circuit derivation (lazy CNOT tracking over GF(2)).
// Physical index p (10 bits): lane = p>>4 (bits 9..4), reg slot = p&15.
// Pack: reg bit0 = slot inside v2f; pair index j = slot>>1 (3 bits).
// ---------------------------------------------------------------------------
struct GateC { unsigned prt, sel; };
struct CircuitT { GateC g[4][10]; unsigned srow[10]; };

constexpr CircuitT make_circuit() {
  CircuitT C{};
  unsigned row[10], col[10];
  for (int b = 0; b < 10; ++b) { row[b] = 1u << b; col[b] = 1u << b; }
  for (int l = 0; l < 4; ++l) {
    for (int w = 0; w < 10; ++w) {
      C.g[l][w].prt = col[9 - w];
      C.g[l][w].sel = row[9 - w];
    }
    const int r = (l % 9) + 1;
    for (int w = 0; w < 10; ++w) {
      const int c = w, t = (w + r) % 10;
      const int bc = 9 - c, bt = 9 - t;
      row[bt] ^= row[bc];
      col[bc] ^= col[bt];
    }
  }
  for (int i = 0; i < 10; ++i) C.srow[i] = row[9 - i];
  return C;
}
constexpr CircuitT CIRC = make_circuit();

constexpr unsigned long long make_sbits() {
  unsigned long long b = 0;
  for (int l = 0; l < 4; ++l)
    for (int w = 0; w < 10; ++w)
      if (CIRC.g[l][w].sel & 1u) b |= 1ull << (l * 10 + w);
  return b;
}
constexpr unsigned long long SBITS = make_sbits();

// ---------------- cross-lane primitives ----------------
template<int CTRL>
__device__ __forceinline__ float dppf(float v) {
  const int i = __float_as_int(v);
  return __int_as_float(__builtin_amdgcn_update_dpp(i, i, CTRL, 0xF, 0xF, false));
}

// xor over low-4 lane bits via DPP chains (quad_perm / half_mirror / mirror)
template<int LOW>
__device__ __forceinline__ float dpp_low(float v) {
  static_assert(LOW >= 0 && LOW <= 15, "bad mask");
  if constexpr (LOW == 0) return v;
  else if constexpr (LOW == 1) return dppf<0xB1>(v);        // quad [1,0,3,2]
  else if constexpr (LOW == 2) return dppf<0x4E>(v);        // quad [2,3,0,1]
  else if constexpr (LOW == 3) return dppf<0x1B>(v);        // quad [3,2,1,0]
  else if constexpr (LOW == 7) return dppf<0x141>(v);       // row_half_mirror
  else if constexpr (LOW == 15) return dppf<0x140>(v);      // row_mirror
  else if constexpr (LOW >= 4 && LOW <= 6) return dpp_low<LOW ^ 7>(dppf<0x141>(v));
  else return dpp_low<LOW ^ 15>(dppf<0x140>(v));            // 8..14
}

constexpr int dpp_ops_low(int low) {
  if (low == 0) return 0;
  if (low == 1 || low == 2 || low == 3 || low == 7 || low == 15) return 1;
  if ((low >= 4 && low <= 6) || low == 8 || (low >= 12 && low <= 14)) return 2;
  return 3;
}
constexpr int valu_cost(int M) {
#if !USE_PERMLANE
  if (M & 48) return 99;
#endif
  return ((M & 32) ? 3 : 0) + ((M & 16) ? 3 : 0) + dpp_ops_low(M & 15);
}

#if USE_PERMLANE
__device__ __forceinline__ float xor16f(float v, int lane) {
  auto r = __builtin_amdgcn_permlane16_swap(__float_as_uint(v), __float_as_uint(v), false, false);
  return (lane & 16) ? __uint_as_float(r[0]) : __uint_as_float(r[1]);
}
__device__ __forceinline__ float xor32f(float v, int lane) {
  auto r = __builtin_amdgcn_permlane32_swap(__float_as_uint(v), __float_as_uint(v), false, false);
  return (lane & 32) ? __uint_as_float(r[0]) : __uint_as_float(r[1]);
}
#else
__device__ __forceinline__ float xor16f(float v, int lane) { return __shfl_xor(v, 16, 64); }
__device__ __forceinline__ float xor32f(float v, int lane) { return __shfl_xor(v, 32, 64); }
#endif

__device__ __forceinline__ float shflx(float v, int m) { return __shfl_xor(v, m, 64); }

// generic lane-xor shuffle: VALU chain if cheap, else 1 DS op
template<int M>
__device__ __forceinline__ float lshuf(float v, int lane, int bpa) {
  if constexpr (valu_cost(M) >= 5) {
    if constexpr ((M & 32) != 0) {
      return __int_as_float(__builtin_amdgcn_ds_bpermute(bpa, __float_as_int(v)));
    } else {
      return __int_as_float(__builtin_amdgcn_ds_swizzle(__float_as_int(v), 0x1F | (M << 10)));
    }
  } else {
    float t = v;
    if constexpr ((M & 32) != 0) t = xor32f(t, lane);
    if constexpr ((M & 16) != 0) t = xor16f(t, lane);
    if constexpr ((M & 15) != 0) t = dpp_low<M & 15>(t);
    return t;
  }
}

// full 64-lane sum, broadcast to all lanes; 0 DS ops
__device__ __forceinline__ float wave_sum(float v, int lane) {
  v += dppf<0xB1>(v);
  v += dppf<0x4E>(v);
  v += dppf<0x141>(v);
  v += dppf<0x140>(v);
#if USE_PERMLANE
  { auto r = __builtin_amdgcn_permlane16_swap(__float_as_uint(v), __float_as_uint(v), false, false);
    v = __uint_as_float(r[0]) + __uint_as_float(r[1]); }
  { auto r = __builtin_amdgcn_permlane32_swap(__float_as_uint(v), __float_as_uint(v), false, false);
    v = __uint_as_float(r[0]) + __uint_as_float(r[1]); }
#else
  v += shflx(v, 16);
  v += shflx(v, 32);
#endif
  return v;
}

// ---------------- packed fp32 primitives ----------------
__device__ __forceinline__ v2f pk_mul(v2f a, v2f b) {
  v2f d; asm("v_pk_mul_f32 %0, %1, %2" : "=v"(d) : "v"(a), "v"(b)); return d;
}
__device__ __forceinline__ v2f pk_fma(v2f a, v2f b, v2f c) {
  v2f d; asm("v_pk_fma_f32 %0, %1, %2, %3" : "=v"(d) : "v"(a), "v"(b), "v"(c)); return d;
}
// partner-term fma: optionally reads src0 with halves swapped (slot-swap gates)
template<bool SW>
__device__ __forceinline__ v2f pk_fma_p(v2f p, v2f c, v2f acc) {
  v2f d;
  if constexpr (SW)
    asm("v_pk_fma_f32 %0, %1, %2, %3 op_sel:[1,0,0] op_sel_hi:[0,1,1]"
        : "=v"(d) : "v"(p), "v"(c), "v"(acc));
  else
    asm("v_pk_fma_f32 %0, %1, %2, %3" : "=v"(d) : "v"(p), "v"(c), "v"(acc));
  return d;
}

struct CSet { v2f Or, Oi, mOi, Pr, Pi, mPi; };

__device__ __forceinline__ CSet load_cset(const v4f* vb) {
  const v4f qa = vb[0], qb = vb[1], qc = vb[2];
  CSet s;
  s.Or  = __builtin_shufflevector(qa, qa, 0, 1);
  s.Oi  = __builtin_shufflevector(qa, qa, 2, 3);
  s.mOi = __builtin_shufflevector(qb, qb, 0, 1);
  s.Pr  = __builtin_shufflevector(qb, qb, 2, 3);
  s.Pi  = __builtin_shufflevector(qc, qc, 0, 1);
  s.mPi = __builtin_shufflevector(qc, qc, 2, 3);
  return s;
}

// new = O*own + P*partner  (per-slot coeff vectors; SW swaps partner slots)
template<bool SW>
__device__ __forceinline__ void cupdate(v2f Rj, v2f Ij, v2f pR, v2f pI,
                                        const CSet& s, v2f& nR, v2f& nI) {
  nR = pk_mul(Rj, s.Or);
  nR = pk_fma(Ij, s.mOi, nR);
  nR = pk_fma_p<SW>(pR, s.Pr, nR);
  nR = pk_fma_p<SW>(pI, s.mPi, nR);
  nI = pk_mul(Ij, s.Or);
  nI = pk_fma(Rj, s.Oi, nI);
  nI = pk_fma_p<SW>(pI, s.Pr, nI);
  nI = pk_fma_p<SW>(pR, s.Pi, nI);
}

template<int L, int W>
__device__ __forceinline__ void gate(v2f R[8], v2f I[8], const float* __restrict__ Ush, int lane) {
  constexpr unsigned PRT = CIRC.g[L][W].prt;
  constexpr unsigned SEL = CIRC.g[L][W].sel;
  constexpr int PLm = (int)(PRT >> 4), PRm = (int)(PRT & 15u);
  constexpr int SLm = (int)(SEL >> 4), SRm = (int)(SEL & 15u);
  constexpr int PRh = PRm >> 1;
  constexpr bool PSW = (PRm & 1) != 0;
  constexpr int SRh = SRm >> 1;

  int hl = 0;
  if constexpr (SLm != 0) hl = __popc(lane & SLm) & 1;

  const v4f* gb = (const v4f*)(Ush + (L * 10 + W) * 32);
  CSet set0 = load_cset(gb + (hl << 2));
  CSet set1;
  if constexpr (SRh != 0) set1 = load_cset(gb + ((hl ^ 1) << 2));
  else                    set1 = set0;

  int bpa = 0;
  if constexpr (valu_cost(PLm) >= 5 && (PLm & 32) != 0) bpa = (lane ^ PLm) << 2;

#pragma unroll
  for (int j = 0; j < 8; ++j) {
    const int jp = j ^ PRh;
    if (jp < j) continue;
    const bool q0 = (__builtin_popcount((unsigned)(j & SRh)) & 1) != 0;
    const CSet& s0 = q0 ? set1 : set0;

    if constexpr (PLm == 0) {
      if constexpr (PRh == 0) {
        v2f nR, nI;
        cupdate<PSW>(R[j], I[j], R[j], I[j], s0, nR, nI);
        R[j] = nR; I[j] = nI;
      } else {
        const bool q1 = (__builtin_popcount((unsigned)(jp & SRh)) & 1) != 0;
        const CSet& s1 = q1 ? set1 : set0;
        v2f nR0, nI0, nR1, nI1;
        cupdate<PSW>(R[j], I[j], R[jp], I[jp], s0, nR0, nI0);
        cupdate<PSW>(R[jp], I[jp], R[j], I[j], s1, nR1, nI1);
        R[j] = nR0; I[j] = nI0; R[jp] = nR1; I[jp] = nI1;
      }
    } else {
      if constexpr (PRh == 0) {
        v2f pR, pI;
        pR.x = lshuf<PLm>(R[j].x, lane, bpa); pR.y = lshuf<PLm>(R[j].y, lane, bpa);
        pI.x = lshuf<PLm>(I[j].x, lane, bpa); pI.y = lshuf<PLm>(I[j].y, lane, bpa);
        v2f nR, nI;
        cupdate<PSW>(R[j], I[j], pR, pI, s0, nR, nI);
        R[j] = nR; I[j] = nI;
      } else {
        const bool q1 = (__builtin_popcount((unsigned)(jp & SRh)) & 1) != 0;
        const CSet& s1 = q1 ? set1 : set0;
        v2f pR0, pI0, pR1, pI1;
        pR0.x = lshuf<PLm>(R[jp].x, lane, bpa); pR0.y = lshuf<PLm>(R[jp].y, lane, bpa);
        pI0.x = lshuf<PLm>(I[jp].x, lane, bpa); pI0.y = lshuf<PLm>(I[jp].y, lane, bpa);
        pR1.x = lshuf<PLm>(R[j].x, lane, bpa);  pR1.y = lshuf<PLm>(R[j].y, lane, bpa);
        pI1.x = lshuf<PLm>(I[j].x, lane, bpa);  pI1.y = lshuf<PLm>(I[j].y, lane, bpa);
        v2f nR0, nI0, nR1, nI1;
        cupdate<PSW>(R[j], I[j], pR0, pI0, s0, nR0, nI0);
        cupdate<PSW>(R[jp], I[jp], pR1, pI1, s1, nR1, nI1);
        R[j] = nR0; I[j] = nI0; R[jp] = nR1; I[jp] = nI1;
      }
    }
  }
}

template<int L, int W>
__device__ __forceinline__ void layer_from(v2f R[8], v2f I[8], const float* __restrict__ Ush, int lane) {
  if constexpr (W < 10) {
    gate<L, W>(R, I, Ush, lane);
    layer_from<L, W + 1>(R, I, Ush, lane);
  }
}

// ---------------- main kernel: one wave per sample ----------------
__global__ __launch_bounds__(256, 4) void qnn_kernel(
    const float* __restrict__ x, const float* __restrict__ Wpre,
    const float* __restrict__ bpre, const float* __restrict__ qw,
    const float* __restrict__ Wpost, const float* __restrict__ bpost,
    float* __restrict__ out)
{
  __shared__ __align__(16) float Ush[40 * 32];

  const int tid = threadIdx.x;
  // Per gate: 2 variants x 3 float4 of per-slot coefficients (batch-uniform).
  // Variant v, slot t holds class c = v ^ (t & s), s = SRm&1.
  // O(c) = c ? (Dr,Di) : (A,0); P(c) = c ? (Cr,Ci) : (Br,Bi).
  if (tid < 40) {
    const float phi = qw[tid * 3 + 0];
    const float th  = qw[tid * 3 + 1];
    const float om  = qw[tid * 3 + 2];
    const float c = cosf(0.5f * th), s_ = sinf(0.5f * th);
    const float A  = c;
    const float Br = -cosf(phi) * s_, Bi = -sinf(phi) * s_;
    const float Cr =  cosf(om)  * s_, Ci =  sinf(om)  * s_;
    const float Dr =  cosf(phi + om) * c, Di = sinf(phi + om) * c;
    const int s = (int)((SBITS >> tid) & 1ull);
    float* gbv = &Ush[tid * 32];
#pragma unroll
    for (int v = 0; v < 2; ++v) {
      const int c0 = v, c1 = v ^ s;
      float* p = gbv + v * 16;
      const float Or0 = c0 ? Dr : A,   Or1 = c1 ? Dr : A;
      const float Oi0 = c0 ? Di : 0.f, Oi1 = c1 ? Di : 0.f;
      const float Pr0 = c0 ? Cr : Br,  Pr1 = c1 ? Cr : Br;
      const float Pi0 = c0 ? Ci : Bi,  Pi1 = c1 ? Ci : Bi;
      p[0] = Or0;  p[1] = Or1;  p[2]  = Oi0;  p[3]  = Oi1;
      p[4] = -Oi0; p[5] = -Oi1; p[6]  = Pr0;  p[7]  = Pr1;
      p[8] = Pi0;  p[9] = Pi1;  p[10] = -Pi0; p[11] = -Pi1;
    }
  }
  __syncthreads();

  const int lane = tid & 63;
  const int b = blockIdx.x * 4 + (tid >> 6);

  // ---- pre-net: angles = tanh(x @ Wpre^T + bpre) ----
  const float* xrow = x + (size_t)b * 128;
  const float x0 = xrow[lane];
  const float x1 = xrow[lane + 64];
  float cw[10], sw[10];
#pragma unroll
  for (int w = 0; w < 10; ++w) {
    float p = fmaf(x0, Wpre[w * 128 + lane], x1 * Wpre[w * 128 + 64 + lane]);
    p = wave_sum(p, lane);
    const float e = __expf(2.f * (p + bpre[w]));
    const float ang = 1.f - 2.f * __builtin_amdgcn_rcpf(e + 1.f);
    const float h = 0.5f * ang;
    cw[w] = __cosf(h);
    sw[w] = __sinf(h);
  }

  // ---- embedding: psi[k] = (prod_w m_w) * (-i)^popcount(k), SoA packed ----
  float ml = 1.f;
#pragma unroll
  for (int w = 0; w < 6; ++w)
    ml *= ((lane >> (5 - w)) & 1) ? sw[w] : cw[w];
  const int pm = __popc(lane) & 3;
  const float phr  = (pm == 0) ? ml : ((pm == 2) ? -ml : 0.f);
  const float phiv = (pm == 1) ? -ml : ((pm == 3) ? ml : 0.f);
  const v2f ph2[4] = { {phr, phiv}, {phiv, -phr}, {-phr, -phiv}, {-phiv, phr} };

  const float mh4[4]  = { cw[6]*cw[7], cw[6]*sw[7], sw[6]*cw[7], sw[6]*sw[7] };
  const float mlo4[4] = { cw[8]*cw[9], cw[8]*sw[9], sw[8]*cw[9], sw[8]*sw[9] };

  v2f R[8], I[8];
#pragma unroll
  for (int j = 0; j < 8; ++j) {
    const int r0 = 2 * j, r1 = 2 * j + 1;
    const float m0 = mh4[r0 >> 2] * mlo4[r0 & 3];
    const float m1 = mh4[r1 >> 2] * mlo4[r1 & 3];
    const int p0 = __popc(r0) & 3, p1 = __popc(r1) & 3;
    R[j] = v2f{ph2[p0].x * m0, ph2[p1].x * m1};
    I[j] = v2f{ph2[p0].y * m0, ph2[p1].y * m1};
  }

  // ---- 40 generalized Rot gates (all CNOTs folded into masks) ----
  layer_from<0, 0>(R, I, Ush, lane);
  layer_from<1, 0>(R, I, Ush, lane);
  layer_from<2, 0>(R, I, Ush, lane);
  layer_from<3, 0>(R, I, Ush, lane);

  // ---- epilogue: acc = sum_p |a|^2 * g(p); g via 16-pt WHT over reg bits ----
  float Wl[10];
#pragma unroll
  for (int i = 0; i < 10; ++i) {
    const int sl = (int)(CIRC.srow[i] >> 4);
    const int par = __popc(lane & sl) & 1;
    const float wv = Wpost[i];
    Wl[i] = par ? -wv : wv;
  }
  float G[16];
#pragma unroll
  for (int m = 0; m < 16; ++m) G[m] = 0.f;
#pragma unroll
  for (int i = 0; i < 10; ++i) G[CIRC.srow[i] & 15u] += Wl[i];
#pragma unroll
  for (int bit = 1; bit < 16; bit <<= 1) {
#pragma unroll
    for (int m = 0; m < 16; ++m) {
      if (!(m & bit)) {
        const float t = G[m];
        G[m] = t + G[m ^ bit];
        G[m ^ bit] = t - G[m ^ bit];
      }
    }
  }

  float acc = 0.f;
#pragma unroll
  for (int r = 0; r < 16; ++r) {
    const int j = r >> 1;
    const float rr = (r & 1) ? R[j].y : R[j].x;
    const float ii = (r & 1) ? I[j].y : I[j].x;
    acc = fmaf(fmaf(rr, rr, ii * ii), G[r], acc);
  }
  acc = wave_sum(acc, lane);

  if (lane == 0) {
    const float z = acc + bpost[0];
    out[b] = __builtin_amdgcn_rcpf(1.f + __expf(-z));
  }
}

extern "C" void kernel_launch(void* const* d_in, const int* in_sizes, int n_in,
                              void* d_out, int out_size, void* d_ws, size_t ws_size,
                              hipStream_t stream) {
  const float* x     = (const float*)d_in[0];
  const float* Wpre  = (const float*)d_in[1];
  const float* bpre  = (const float*)d_in[2];
  const float* qw    = (const float*)d_in[3];
  const float* Wpost = (const float*)d_in[4];
  const float* bpost = (const float*)d_in[5];
  float* out = (float*)d_out;

  (void)in_sizes; (void)n_in; (void)out_size; (void)d_ws; (void)ws_size;

  qnn_kernel<<<BATCH / 4, 256, 0, stream>>>(x, Wpre, bpre, qw, Wpost, bpost, out);
}

// Round 6
// 262.147 us; speedup vs baseline: 1.9344x; 1.2117x over previous
//
#include <hip/hip_runtime.h>
#include <math.h>

#define BATCH 32768

typedef float v2f __attribute__((ext_vector_type(2)));
typedef float v4f __attribute__((ext_vector_type(4)));

#if defined(__has_builtin)
#if __has_builtin(__builtin_amdgcn_permlane32_swap) && __has_builtin(__builtin_amdgcn_permlane16_swap)
#define USE_PERMLANE 1
#else
#define USE_PERMLANE 0
#endif
#else
#define USE_PERMLANE 0
#endif

// ---------------------------------------------------------------------------
// Compile-time circuit derivation (lazy CNOT tracking over GF(2)).
// Physical index p (10 bits): lane = p>>4 (bits 9..4), reg slot = p&15.
// Pack: reg bit0 = slot inside v2f; pair index j = slot>>1 (3 bits).
// Layer 0's Rot gates are folded into the embedding (state is still a product
// state and A==I there), so only layers 1..3 run as generalized gates.
// ---------------------------------------------------------------------------
struct GateC { unsigned prt, sel; };
struct CircuitT { GateC g[4][10]; unsigned srow[10]; };

constexpr CircuitT make_circuit() {
  CircuitT C{};
  unsigned row[10], col[10];
  for (int b = 0; b < 10; ++b) { row[b] = 1u << b; col[b] = 1u << b; }
  for (int l = 0; l < 4; ++l) {
    for (int w = 0; w < 10; ++w) {
      C.g[l][w].prt = col[9 - w];
      C.g[l][w].sel = row[9 - w];
    }
    const int r = (l % 9) + 1;
    for (int w = 0; w < 10; ++w) {
      const int c = w, t = (w + r) % 10;
      const int bc = 9 - c, bt = 9 - t;
      row[bt] ^= row[bc];
      col[bc] ^= col[bt];
    }
  }
  for (int i = 0; i < 10; ++i) C.srow[i] = row[9 - i];
  return C;
}
constexpr CircuitT CIRC = make_circuit();

constexpr unsigned long long make_sbits() {
  unsigned long long b = 0;
  for (int l = 0; l < 4; ++l)
    for (int w = 0; w < 10; ++w)
      if (CIRC.g[l][w].sel & 1u) b |= 1ull << (l * 10 + w);
  return b;
}
constexpr unsigned long long SBITS = make_sbits();

// ---------------- cross-lane primitives ----------------
template<int CTRL>
__device__ __forceinline__ float dppf(float v) {
  const int i = __float_as_int(v);
  return __int_as_float(__builtin_amdgcn_update_dpp(i, i, CTRL, 0xF, 0xF, false));
}

template<int LOW>
__device__ __forceinline__ float dpp_low(float v) {
  static_assert(LOW >= 0 && LOW <= 15, "bad mask");
  if constexpr (LOW == 0) return v;
  else if constexpr (LOW == 1) return dppf<0xB1>(v);        // quad [1,0,3,2]
  else if constexpr (LOW == 2) return dppf<0x4E>(v);        // quad [2,3,0,1]
  else if constexpr (LOW == 3) return dppf<0x1B>(v);        // quad [3,2,1,0]
  else if constexpr (LOW == 7) return dppf<0x141>(v);       // row_half_mirror
  else if constexpr (LOW == 15) return dppf<0x140>(v);      // row_mirror
  else if constexpr (LOW >= 4 && LOW <= 6) return dpp_low<LOW ^ 7>(dppf<0x141>(v));
  else return dpp_low<LOW ^ 15>(dppf<0x140>(v));            // 8..14
}

constexpr int dpp_ops_low(int low) {
  if (low == 0) return 0;
  if (low == 1 || low == 2 || low == 3 || low == 7 || low == 15) return 1;
  if ((low >= 4 && low <= 6) || low == 8 || (low >= 12 && low <= 14)) return 2;
  return 3;
}
// permlane-swap + cndmask = 2 ops per high bit
constexpr int chain_cost(int M) {
#if !USE_PERMLANE
  if (M & 48) return 99;
#endif
  return ((M & 32) ? 2 : 0) + ((M & 16) ? 2 : 0) + dpp_ops_low(M & 15);
}
constexpr bool use_ds_mask(int M) { return chain_cost(M) >= 4; }

#if USE_PERMLANE
__device__ __forceinline__ float xor16f(float v, int lane) {
  auto r = __builtin_amdgcn_permlane16_swap(__float_as_uint(v), __float_as_uint(v), false, false);
  return (lane & 16) ? __uint_as_float(r[0]) : __uint_as_float(r[1]);
}
__device__ __forceinline__ float xor32f(float v, int lane) {
  auto r = __builtin_amdgcn_permlane32_swap(__float_as_uint(v), __float_as_uint(v), false, false);
  return (lane & 32) ? __uint_as_float(r[0]) : __uint_as_float(r[1]);
}
#else
__device__ __forceinline__ float xor16f(float v, int lane) { return __shfl_xor(v, 16, 64); }
__device__ __forceinline__ float xor32f(float v, int lane) { return __shfl_xor(v, 32, 64); }
#endif

__device__ __forceinline__ float shflx(float v, int m) { return __shfl_xor(v, m, 64); }

// generic lane-xor shuffle: cheap VALU chain, else 1 DS op
template<int M>
__device__ __forceinline__ float lshuf(float v, int lane, int bpa) {
  if constexpr (use_ds_mask(M)) {
    if constexpr ((M & 32) != 0) {
      return __int_as_float(__builtin_amdgcn_ds_bpermute(bpa, __float_as_int(v)));
    } else {
      return __int_as_float(__builtin_amdgcn_ds_swizzle(__float_as_int(v), 0x1F | (M << 10)));
    }
  } else {
    float t = v;
    if constexpr ((M & 32) != 0) t = xor32f(t, lane);
    if constexpr ((M & 16) != 0) t = xor16f(t, lane);
    if constexpr ((M & 15) != 0) t = dpp_low<M & 15>(t);
    return t;
  }
}

// full 64-lane sum, broadcast; 0 DS ops
__device__ __forceinline__ float wave_sum(float v, int lane) {
  v += dppf<0xB1>(v);
  v += dppf<0x4E>(v);
  v += dppf<0x141>(v);
  v += dppf<0x140>(v);
#if USE_PERMLANE
  { auto r = __builtin_amdgcn_permlane16_swap(__float_as_uint(v), __float_as_uint(v), false, false);
    v = __uint_as_float(r[0]) + __uint_as_float(r[1]); }
  { auto r = __builtin_amdgcn_permlane32_swap(__float_as_uint(v), __float_as_uint(v), false, false);
    v = __uint_as_float(r[0]) + __uint_as_float(r[1]); }
#else
  v += shflx(v, 16);
  v += shflx(v, 32);
#endif
  return v;
}

// ---------------- packed fp32 primitives ----------------
__device__ __forceinline__ v2f pk_mul(v2f a, v2f b) {
  v2f d; asm("v_pk_mul_f32 %0, %1, %2" : "=v"(d) : "v"(a), "v"(b)); return d;
}
__device__ __forceinline__ v2f pk_fma(v2f a, v2f b, v2f c) {
  v2f d; asm("v_pk_fma_f32 %0, %1, %2, %3" : "=v"(d) : "v"(a), "v"(b), "v"(c)); return d;
}
template<bool SW>
__device__ __forceinline__ v2f pk_fma_p(v2f p, v2f c, v2f acc) {
  v2f d;
  if constexpr (SW)
    asm("v_pk_fma_f32 %0, %1, %2, %3 op_sel:[1,0,0] op_sel_hi:[0,1,1]"
        : "=v"(d) : "v"(p), "v"(c), "v"(acc));
  else
    asm("v_pk_fma_f32 %0, %1, %2, %3" : "=v"(d) : "v"(p), "v"(c), "v"(acc));
  return d;
}

struct CSet { v2f Or, Oi, mOi, Pr, Pi, mPi; };

__device__ __forceinline__ CSet load_cset(const v4f* vb) {
  const v4f qa = vb[0], qb = vb[1], qc = vb[2];
  CSet s;
  s.Or  = __builtin_shufflevector(qa, qa, 0, 1);
  s.Oi  = __builtin_shufflevector(qa, qa, 2, 3);
  s.mOi = __builtin_shufflevector(qb, qb, 0, 1);
  s.Pr  = __builtin_shufflevector(qb, qb, 2, 3);
  s.Pi  = __builtin_shufflevector(qc, qc, 0, 1);
  s.mPi = __builtin_shufflevector(qc, qc, 2, 3);
  return s;
}

// reg-local full-pk update: new = O*own + P*partner (SW swaps partner slots)
template<bool SW>
__device__ __forceinline__ void cupdate(v2f Rj, v2f Ij, v2f pR, v2f pI,
                                        const CSet& s, v2f& nR, v2f& nI) {
  nR = pk_mul(Rj, s.Or);
  nR = pk_fma(Ij, s.mOi, nR);
  nR = pk_fma_p<SW>(pR, s.Pr, nR);
  nR = pk_fma_p<SW>(pI, s.mPi, nR);
  nI = pk_mul(Ij, s.Or);
  nI = pk_fma(Rj, s.Oi, nI);
  nI = pk_fma_p<SW>(pI, s.Pr, nI);
  nI = pk_fma_p<SW>(pR, s.Pi, nI);
}

// lane-crossing update: own terms pk, partner terms scalar (no v2f assembly)
__device__ __forceinline__ void applyP(v2f& Rj, v2f& Ij, const CSet& s,
                                       float pRx, float pRy, float pIx, float pIy) {
  v2f tR = pk_mul(Rj, s.Or);
  tR = pk_fma(Ij, s.mOi, tR);
  v2f tI = pk_mul(Ij, s.Or);
  tI = pk_fma(Rj, s.Oi, tI);
  tR.x = fmaf(s.Pr.x, pRx, tR.x); tR.x = fmaf(s.mPi.x, pIx, tR.x);
  tR.y = fmaf(s.Pr.y, pRy, tR.y); tR.y = fmaf(s.mPi.y, pIy, tR.y);
  tI.x = fmaf(s.Pr.x, pIx, tI.x); tI.x = fmaf(s.Pi.x, pRx, tI.x);
  tI.y = fmaf(s.Pr.y, pIy, tI.y); tI.y = fmaf(s.Pi.y, pRy, tI.y);
  Rj = tR; Ij = tI;
}

template<int L, int W>
__device__ __forceinline__ void gate(v2f R[8], v2f I[8], const float* __restrict__ Ush, int lane) {
  constexpr unsigned PRT = CIRC.g[L][W].prt;
  constexpr unsigned SEL = CIRC.g[L][W].sel;
  constexpr int PLm = (int)(PRT >> 4), PRm = (int)(PRT & 15u);
  constexpr int SLm = (int)(SEL >> 4), SRm = (int)(SEL & 15u);
  constexpr int PRh = PRm >> 1;
  constexpr bool PSW = (PRm & 1) != 0;
  constexpr int SRh = SRm >> 1;

  int hl = 0;
  if constexpr (SLm != 0) hl = __popc(lane & SLm) & 1;

  const v4f* gb = (const v4f*)(Ush + (L * 10 + W) * 32);
  CSet set0 = load_cset(gb + (hl << 2));
  CSet set1;
  if constexpr (SRh != 0) set1 = load_cset(gb + ((hl ^ 1) << 2));
  else                    set1 = set0;

  int bpa = 0;
  if constexpr (use_ds_mask(PLm) && (PLm & 32) != 0) bpa = (lane ^ PLm) << 2;

  if constexpr (PLm == 0) {
    // pure reg-space gate: full-pk path
#pragma unroll
    for (int j = 0; j < 8; ++j) {
      const int jp = j ^ PRh;
      if (PRh != 0 && jp < j) continue;
      const bool q0 = (__builtin_popcount((unsigned)(j & SRh)) & 1) != 0;
      const CSet& s0 = q0 ? set1 : set0;
      if constexpr (PRh == 0) {
        v2f nR, nI;
        cupdate<PSW>(R[j], I[j], R[j], I[j], s0, nR, nI);
        R[j] = nR; I[j] = nI;
      } else {
        const bool q1 = (__builtin_popcount((unsigned)(jp & SRh)) & 1) != 0;
        const CSet& s1 = q1 ? set1 : set0;
        v2f nR0, nI0, nR1, nI1;
        cupdate<PSW>(R[j], I[j], R[jp], I[jp], s0, nR0, nI0);
        cupdate<PSW>(R[jp], I[jp], R[j], I[j], s1, nR1, nI1);
        R[j] = nR0; I[j] = nI0; R[jp] = nR1; I[jp] = nI1;
      }
    }
  } else if constexpr (PRh == 0) {
#pragma unroll
    for (int j = 0; j < 8; ++j) {
      const bool q = (__builtin_popcount((unsigned)(j & SRh)) & 1) != 0;
      const CSet& s = q ? set1 : set0;
      float pRx, pRy, pIx, pIy;
      if constexpr (PSW) {
        pRx = lshuf<PLm>(R[j].y, lane, bpa); pRy = lshuf<PLm>(R[j].x, lane, bpa);
        pIx = lshuf<PLm>(I[j].y, lane, bpa); pIy = lshuf<PLm>(I[j].x, lane, bpa);
      } else {
        pRx = lshuf<PLm>(R[j].x, lane, bpa); pRy = lshuf<PLm>(R[j].y, lane, bpa);
        pIx = lshuf<PLm>(I[j].x, lane, bpa); pIy = lshuf<PLm>(I[j].y, lane, bpa);
      }
      applyP(R[j], I[j], s, pRx, pRy, pIx, pIy);
    }
  } else {
#pragma unroll
    for (int j = 0; j < 8; ++j) {
      const int jp = j ^ PRh;
      if (jp < j) continue;
      const bool q0 = (__builtin_popcount((unsigned)(j & SRh)) & 1) != 0;
      const bool q1 = (__builtin_popcount((unsigned)(jp & SRh)) & 1) != 0;
      const CSet& s0 = q0 ? set1 : set0;
      const CSet& s1 = q1 ? set1 : set0;
      float p0Rx, p0Ry, p0Ix, p0Iy, p1Rx, p1Ry, p1Ix, p1Iy;
      if constexpr (PSW) {
        p0Rx = lshuf<PLm>(R[jp].y, lane, bpa); p0Ry = lshuf<PLm>(R[jp].x, lane, bpa);
        p0Ix = lshuf<PLm>(I[jp].y, lane, bpa); p0Iy = lshuf<PLm>(I[jp].x, lane, bpa);
        p1Rx = lshuf<PLm>(R[j].y, lane, bpa);  p1Ry = lshuf<PLm>(R[j].x, lane, bpa);
        p1Ix = lshuf<PLm>(I[j].y, lane, bpa);  p1Iy = lshuf<PLm>(I[j].x, lane, bpa);
      } else {
        p0Rx = lshuf<PLm>(R[jp].x, lane, bpa); p0Ry = lshuf<PLm>(R[jp].y, lane, bpa);
        p0Ix = lshuf<PLm>(I[jp].x, lane, bpa); p0Iy = lshuf<PLm>(I[jp].y, lane, bpa);
        p1Rx = lshuf<PLm>(R[j].x, lane, bpa);  p1Ry = lshuf<PLm>(R[j].y, lane, bpa);
        p1Ix = lshuf<PLm>(I[j].x, lane, bpa);  p1Iy = lshuf<PLm>(I[j].y, lane, bpa);
      }
      applyP(R[j], I[j], s0, p0Rx, p0Ry, p0Ix, p0Iy);
      applyP(R[jp], I[jp], s1, p1Rx, p1Ry, p1Ix, p1Iy);
    }
  }
}

template<int L, int W>
__device__ __forceinline__ void layer_from(v2f R[8], v2f I[8], const float* __restrict__ Ush, int lane) {
  if constexpr (W < 10) {
    gate<L, W>(R, I, Ush, lane);
    layer_from<L, W + 1>(R, I, Ush, lane);
  }
}

// ---------------- main kernel: one wave per sample ----------------
__global__ __launch_bounds__(256, 4) void qnn_kernel(
    const float* __restrict__ x, const float* __restrict__ Wpre,
    const float* __restrict__ bpre, const float* __restrict__ qw,
    const float* __restrict__ Wpost, const float* __restrict__ bpost,
    float* __restrict__ out)
{
  __shared__ __align__(16) float Ush[40 * 32];

  const int tid = threadIdx.x;
  // tid<10 (layer 0): store raw {A,Br,Bi,Cr,Ci,Dr,Di} (folded into embedding).
  // tid 10..39: 2 variants x 3 float4 per-slot coefficient vectors.
  if (tid < 40) {
    const float phi = qw[tid * 3 + 0];
    const float th  = qw[tid * 3 + 1];
    const float om  = qw[tid * 3 + 2];
    const float c = cosf(0.5f * th), s_ = sinf(0.5f * th);
    const float A  = c;
    const float Br = -cosf(phi) * s_, Bi = -sinf(phi) * s_;
    const float Cr =  cosf(om)  * s_, Ci =  sinf(om)  * s_;
    const float Dr =  cosf(phi + om) * c, Di = sinf(phi + om) * c;
    float* gbv = &Ush[tid * 32];
    if (tid < 10) {
      gbv[0] = A;  gbv[1] = Br; gbv[2] = Bi; gbv[3] = Cr;
      gbv[4] = Ci; gbv[5] = Dr; gbv[6] = Di; gbv[7] = 0.f;
    } else {
      const int s = (int)((SBITS >> tid) & 1ull);
#pragma unroll
      for (int v = 0; v < 2; ++v) {
        const int c0 = v, c1 = v ^ s;
        float* p = gbv + v * 16;
        const float Or0 = c0 ? Dr : A,   Or1 = c1 ? Dr : A;
        const float Oi0 = c0 ? Di : 0.f, Oi1 = c1 ? Di : 0.f;
        const float Pr0 = c0 ? Cr : Br,  Pr1 = c1 ? Cr : Br;
        const float Pi0 = c0 ? Ci : Bi,  Pi1 = c1 ? Ci : Bi;
        p[0] = Or0;  p[1] = Or1;  p[2]  = Oi0;  p[3]  = Oi1;
        p[4] = -Oi0; p[5] = -Oi1; p[6]  = Pr0;  p[7]  = Pr1;
        p[8] = Pi0;  p[9] = Pi1;  p[10] = -Pi0; p[11] = -Pi1;
      }
    }
  }
  __syncthreads();

  const int lane = tid & 63;
  const int b = blockIdx.x * 4 + (tid >> 6);

  // ---- pre-net: angles = tanh(x @ Wpre^T + bpre) ----
  const float* xrow = x + (size_t)b * 128;
  const float x0 = xrow[lane];
  const float x1 = xrow[lane + 64];
  float cw[10], sw[10];
#pragma unroll
  for (int w = 0; w < 10; ++w) {
    float p = fmaf(x0, Wpre[w * 128 + lane], x1 * Wpre[w * 128 + 64 + lane]);
    p = wave_sum(p, lane);
    const float e = __expf(2.f * (p + bpre[w]));
    const float ang = 1.f - 2.f * __builtin_amdgcn_rcpf(e + 1.f);
    const float h = 0.5f * ang;
    cw[w] = __cosf(h);
    sw[w] = __sinf(h);
  }

  // ---- embedding with layer-0 fold: psi = tensor_w [Rot_w0 . (cos h, -i sin h)] ----
  float u0r[10], u0i[10], u1r[10], u1i[10];
#pragma unroll
  for (int w = 0; w < 10; ++w) {
    const float* q = &Ush[w * 32];
    const float A = q[0], Br = q[1], Bi = q[2], Cr = q[3], Ci = q[4], Dr = q[5], Di = q[6];
    const float ch = cw[w], sh = sw[w];
    u0r[w] = fmaf(A, ch, Bi * sh);     // u00*c + u01*(-i s), real
    u0i[w] = -Br * sh;                 // imag
    u1r[w] = fmaf(Cr, ch, Di * sh);    // u10*c + u11*(-i s), real
    u1i[w] = fmaf(Ci, ch, -Dr * sh);   // imag
  }

  // lane factor: wires 0..5 <-> lane bits 5..0
  float Lr, Li;
  {
    const int b0 = (lane >> 5) & 1;
    Lr = b0 ? u1r[0] : u0r[0];
    Li = b0 ? u1i[0] : u0i[0];
  }
#pragma unroll
  for (int w = 1; w < 6; ++w) {
    const int bb = (lane >> (5 - w)) & 1;
    const float ar = bb ? u1r[w] : u0r[w];
    const float ai = bb ? u1i[w] : u0i[w];
    const float nr = fmaf(Lr, ar, -Li * ai);
    const float ni = fmaf(Lr, ai, Li * ar);
    Lr = nr; Li = ni;
  }

  // reg factors: wires 6,7 -> t4[r>>2], wires 8,9 -> s4[r&3]; ls = s4 * L
  float t4r[4], t4i[4], lsr[4], lsi[4];
#pragma unroll
  for (int a = 0; a < 2; ++a) {
#pragma unroll
    for (int c2 = 0; c2 < 2; ++c2) {
      const int k = (a << 1) | c2;
      const float ar6 = a ? u1r[6] : u0r[6], ai6 = a ? u1i[6] : u0i[6];
      const float ar7 = c2 ? u1r[7] : u0r[7], ai7 = c2 ? u1i[7] : u0i[7];
      t4r[k] = fmaf(ar6, ar7, -ai6 * ai7);
      t4i[k] = fmaf(ar6, ai7, ai6 * ar7);
      const float ar8 = a ? u1r[8] : u0r[8], ai8 = a ? u1i[8] : u0i[8];
      const float ar9 = c2 ? u1r[9] : u0r[9], ai9 = c2 ? u1i[9] : u0i[9];
      const float s4r = fmaf(ar8, ar9, -ai8 * ai9);
      const float s4i = fmaf(ar8, ai9, ai8 * ar9);
      lsr[k] = fmaf(s4r, Lr, -s4i * Li);
      lsi[k] = fmaf(s4r, Li, s4i * Lr);
    }
  }

  v2f R[8], I[8];
#pragma unroll
  for (int j = 0; j < 8; ++j) {
    const int r0 = 2 * j, r1 = 2 * j + 1;
    R[j].x = fmaf(t4r[r0 >> 2], lsr[r0 & 3], -t4i[r0 >> 2] * lsi[r0 & 3]);
    I[j].x = fmaf(t4r[r0 >> 2], lsi[r0 & 3],  t4i[r0 >> 2] * lsr[r0 & 3]);
    R[j].y = fmaf(t4r[r1 >> 2], lsr[r1 & 3], -t4i[r1 >> 2] * lsi[r1 & 3]);
    I[j].y = fmaf(t4r[r1 >> 2], lsi[r1 & 3],  t4i[r1 >> 2] * lsr[r1 & 3]);
  }

  // ---- layers 1..3 (layer 0 folded above; CNOTs folded into masks) ----
  layer_from<1, 0>(R, I, Ush, lane);
  layer_from<2, 0>(R, I, Ush, lane);
  layer_from<3, 0>(R, I, Ush, lane);

  // ---- epilogue: acc = sum_p |a|^2 * g(p); g via 16-pt WHT over reg bits ----
  float Wl[10];
#pragma unroll
  for (int i = 0; i < 10; ++i) {
    const int sl = (int)(CIRC.srow[i] >> 4);
    const int par = __popc(lane & sl) & 1;
    const float wv = Wpost[i];
    Wl[i] = par ? -wv : wv;
  }
  float G[16];
#pragma unroll
  for (int m = 0; m < 16; ++m) G[m] = 0.f;
#pragma unroll
  for (int i = 0; i < 10; ++i) G[CIRC.srow[i] & 15u] += Wl[i];
#pragma unroll
  for (int bit = 1; bit < 16; bit <<= 1) {
#pragma unroll
    for (int m = 0; m < 16; ++m) {
      if (!(m & bit)) {
        const float t = G[m];
        G[m] = t + G[m ^ bit];
        G[m ^ bit] = t - G[m ^ bit];
      }
    }
  }

  float acc = 0.f;
#pragma unroll
  for (int r = 0; r < 16; ++r) {
    const int j = r >> 1;
    const float rr = (r & 1) ? R[j].y : R[j].x;
    const float ii = (r & 1) ? I[j].y : I[j].x;
    acc = fmaf(fmaf(rr, rr, ii * ii), G[r], acc);
  }
  acc = wave_sum(acc, lane);

  if (lane == 0) {
    const float z = acc + bpost[0];
    out[b] = __builtin_amdgcn_rcpf(1.f + __expf(-z));
  }
}

extern "C" void kernel_launch(void* const* d_in, const int* in_sizes, int n_in,
                              void* d_out, int out_size, void* d_ws, size_t ws_size,
                              hipStream_t stream) {
  const float* x     = (const float*)d_in[0];
  const float* Wpre  = (const float*)d_in[1];
  const float* bpre  = (const float*)d_in[2];
  const float* qw    = (const float*)d_in[3];
  const float* Wpost = (const float*)d_in[4];
  const float* bpost = (const float*)d_in[5];
  float* out = (float*)d_out;

  (void)in_sizes; (void)n_in; (void)out_size; (void)d_ws; (void)ws_size;

  qnn_kernel<<<BATCH / 4, 256, 0, stream>>>(x, Wpre, bpre, qw, Wpost, bpost, out);
}

// Round 7
// 234.539 us; speedup vs baseline: 2.1621x; 1.1177x over previous
//
#include <hip/hip_runtime.h>
#include <math.h>

#define BATCH 32768

typedef float v4f __attribute__((ext_vector_type(4)));

#if defined(__has_builtin)
#if __has_builtin(__builtin_amdgcn_permlane32_swap) && __has_builtin(__builtin_amdgcn_permlane16_swap)
#define USE_PERMLANE 1
#else
#define USE_PERMLANE 0
#endif
#else
#define USE_PERMLANE 0
#endif

// ---------------------------------------------------------------------------
// Compile-time circuit derivation (lazy CNOT tracking over GF(2)).
// Physical index p (10 bits): lane = p>>4 (bits 9..4), reg slot t = p&15.
// Layer 0's Rots are folded into the embedding; layers 1..3 run as
// generalized pair-mix gates with compile-time partner/select masks.
// ---------------------------------------------------------------------------
struct GateC { unsigned prt, sel; };
struct CircuitT { GateC g[4][10]; unsigned srow[10]; };

constexpr CircuitT make_circuit() {
  CircuitT C{};
  unsigned row[10], col[10];
  for (int b = 0; b < 10; ++b) { row[b] = 1u << b; col[b] = 1u << b; }
  for (int l = 0; l < 4; ++l) {
    for (int w = 0; w < 10; ++w) {
      C.g[l][w].prt = col[9 - w];
      C.g[l][w].sel = row[9 - w];
    }
    const int r = (l % 9) + 1;
    for (int w = 0; w < 10; ++w) {
      const int c = w, t = (w + r) % 10;
      const int bc = 9 - c, bt = 9 - t;
      row[bt] ^= row[bc];
      col[bc] ^= col[bt];
    }
  }
  for (int i = 0; i < 10; ++i) C.srow[i] = row[9 - i];
  return C;
}
constexpr CircuitT CIRC = make_circuit();

// ---------------- cross-lane primitives ----------------
template<int CTRL>
__device__ __forceinline__ float dppf(float v) {
  const int i = __float_as_int(v);
  return __int_as_float(__builtin_amdgcn_update_dpp(i, i, CTRL, 0xF, 0xF, false));
}

template<int LOW>
__device__ __forceinline__ float dpp_low(float v) {
  static_assert(LOW >= 0 && LOW <= 15, "bad mask");
  if constexpr (LOW == 0) return v;
  else if constexpr (LOW == 1) return dppf<0xB1>(v);        // quad [1,0,3,2]
  else if constexpr (LOW == 2) return dppf<0x4E>(v);        // quad [2,3,0,1]
  else if constexpr (LOW == 3) return dppf<0x1B>(v);        // quad [3,2,1,0]
  else if constexpr (LOW == 7) return dppf<0x141>(v);       // row_half_mirror
  else if constexpr (LOW == 15) return dppf<0x140>(v);      // row_mirror
  else if constexpr (LOW >= 4 && LOW <= 6) return dpp_low<LOW ^ 7>(dppf<0x141>(v));
  else return dpp_low<LOW ^ 15>(dppf<0x140>(v));            // 8..14
}

constexpr int dpp_ops_low(int low) {
  if (low == 0) return 0;
  if (low == 1 || low == 2 || low == 3 || low == 7 || low == 15) return 1;
  if ((low >= 4 && low <= 6) || low == 8 || (low >= 12 && low <= 14)) return 2;
  return 3;
}
constexpr int chain_cost(int M) {
#if !USE_PERMLANE
  if (M & 48) return 99;
#endif
  return ((M & 32) ? 2 : 0) + ((M & 16) ? 2 : 0) + dpp_ops_low(M & 15);
}
// VALU is the binding pipe: only single-DPP masks stay on VALU.
constexpr bool use_ds_mask(int M) { return chain_cost(M) >= 2; }

#if USE_PERMLANE
__device__ __forceinline__ float xor16f(float v, int lane) {
  auto r = __builtin_amdgcn_permlane16_swap(__float_as_uint(v), __float_as_uint(v), false, false);
  return (lane & 16) ? __uint_as_float(r[0]) : __uint_as_float(r[1]);
}
__device__ __forceinline__ float xor32f(float v, int lane) {
  auto r = __builtin_amdgcn_permlane32_swap(__float_as_uint(v), __float_as_uint(v), false, false);
  return (lane & 32) ? __uint_as_float(r[0]) : __uint_as_float(r[1]);
}
#else
__device__ __forceinline__ float xor16f(float v, int lane) { return __shfl_xor(v, 16, 64); }
__device__ __forceinline__ float xor32f(float v, int lane) { return __shfl_xor(v, 32, 64); }
#endif

__device__ __forceinline__ float shflx(float v, int m) { return __shfl_xor(v, m, 64); }

// generic lane-xor shuffle: single-DPP if possible, else 1 DS op
template<int M>
__device__ __forceinline__ float lshuf(float v, int lane, int bpa) {
  if constexpr (use_ds_mask(M)) {
    if constexpr ((M & 32) != 0) {
      return __int_as_float(__builtin_amdgcn_ds_bpermute(bpa, __float_as_int(v)));
    } else {
      return __int_as_float(__builtin_amdgcn_ds_swizzle(__float_as_int(v), 0x1F | (M << 10)));
    }
  } else {
    float t = v;
    if constexpr ((M & 32) != 0) t = xor32f(t, lane);
    if constexpr ((M & 16) != 0) t = xor16f(t, lane);
    if constexpr ((M & 15) != 0) t = dpp_low<M & 15>(t);
    return t;
  }
}

// full 64-lane sum, broadcast; 0 DS ops
__device__ __forceinline__ float wave_sum(float v, int lane) {
  v += dppf<0xB1>(v);
  v += dppf<0x4E>(v);
  v += dppf<0x141>(v);
  v += dppf<0x140>(v);
#if USE_PERMLANE
  { auto r = __builtin_amdgcn_permlane16_swap(__float_as_uint(v), __float_as_uint(v), false, false);
    v = __uint_as_float(r[0]) + __uint_as_float(r[1]); }
  { auto r = __builtin_amdgcn_permlane32_swap(__float_as_uint(v), __float_as_uint(v), false, false);
    v = __uint_as_float(r[0]) + __uint_as_float(r[1]); }
#else
  v += shflx(v, 16);
  v += shflx(v, 32);
#endif
  return v;
}

// one amp update: new = O*own + P*partner; s = {Or, Oi, Pr, Pi}
// neg handled by VOP3 src modifiers (free).
__device__ __forceinline__ void updw(float& rr, float& ri, const v4f s,
                                     float a_r, float a_i, float q_r, float q_i) {
  const float nr = fmaf(s[0], a_r, fmaf(-s[1], a_i, fmaf(s[2], q_r, -s[3] * q_i)));
  const float ni = fmaf(s[0], a_i, fmaf( s[1], a_r, fmaf(s[2], q_i,  s[3] * q_r)));
  rr = nr; ri = ni;
}

template<int L, int W>
__device__ __forceinline__ void gate(float ar[16], float ai[16],
                                     const float* __restrict__ Ush, int lane) {
  constexpr unsigned PRT = CIRC.g[L][W].prt;
  constexpr unsigned SEL = CIRC.g[L][W].sel;
  constexpr int PLm = (int)(PRT >> 4), PRm = (int)(PRT & 15u);
  constexpr int SLm = (int)(SEL >> 4), SRm = (int)(SEL & 15u);

  int hl = 0;
  if constexpr (SLm != 0) hl = __popc(lane & SLm) & 1;

  // cA: coeffs for slots with ct=0 (class hl); cB: ct=1 (class hl^1)
  const float* gb = Ush + (L * 10 + W) * 8;
  const v4f cA = *(const v4f*)(gb + (hl << 2));
  v4f cB;
  if constexpr (SRm != 0) cB = *(const v4f*)(gb + ((hl ^ 1) << 2));
  else                    cB = cA;

  int bpa = 0;
  if constexpr (use_ds_mask(PLm) && (PLm & 32) != 0) bpa = (lane ^ PLm) << 2;

  if constexpr (PLm == 0) {
    // register-space gate
    constexpr int LB = PRm & (-PRm);
#pragma unroll
    for (int t0 = 0; t0 < 16; ++t0) {
      if (t0 & LB) continue;
      const int t1 = t0 ^ PRm;
      const bool q0 = (__builtin_popcount((unsigned)(t0 & SRm)) & 1) != 0;
      const bool q1 = (__builtin_popcount((unsigned)(t1 & SRm)) & 1) != 0;
      const v4f s0 = q0 ? cB : cA;
      const v4f s1 = q1 ? cB : cA;
      const float a0r = ar[t0], a0i = ai[t0], a1r = ar[t1], a1i = ai[t1];
      updw(ar[t0], ai[t0], s0, a0r, a0i, a1r, a1i);
      updw(ar[t1], ai[t1], s1, a1r, a1i, a0r, a0i);
    }
  } else if constexpr (PRm == 0) {
    // lane-crossing, same slot
#pragma unroll
    for (int t = 0; t < 16; ++t) {
      const float qr = lshuf<PLm>(ar[t], lane, bpa);
      const float qi = lshuf<PLm>(ai[t], lane, bpa);
      const bool q = (__builtin_popcount((unsigned)(t & SRm)) & 1) != 0;
      const v4f s = q ? cB : cA;
      updw(ar[t], ai[t], s, ar[t], ai[t], qr, qi);
    }
  } else {
    // lane-crossing with slot pairing
    constexpr int LB = PRm & (-PRm);
#pragma unroll
    for (int t0 = 0; t0 < 16; ++t0) {
      if (t0 & LB) continue;
      const int t1 = t0 ^ PRm;
      const float q0r = lshuf<PLm>(ar[t1], lane, bpa);
      const float q0i = lshuf<PLm>(ai[t1], lane, bpa);
      const float q1r = lshuf<PLm>(ar[t0], lane, bpa);
      const float q1i = lshuf<PLm>(ai[t0], lane, bpa);
      const bool q0 = (__builtin_popcount((unsigned)(t0 & SRm)) & 1) != 0;
      const bool q1 = (__builtin_popcount((unsigned)(t1 & SRm)) & 1) != 0;
      const v4f s0 = q0 ? cB : cA;
      const v4f s1 = q1 ? cB : cA;
      const float a0r = ar[t0], a0i = ai[t0], a1r = ar[t1], a1i = ai[t1];
      updw(ar[t0], ai[t0], s0, a0r, a0i, q0r, q0i);
      updw(ar[t1], ai[t1], s1, a1r, a1i, q1r, q1i);
    }
  }
}

template<int L, int W>
__device__ __forceinline__ void layer_from(float ar[16], float ai[16],
                                           const float* __restrict__ Ush, int lane) {
  if constexpr (W < 10) {
    gate<L, W>(ar, ai, Ush, lane);
    layer_from<L, W + 1>(ar, ai, Ush, lane);
  }
}

// ---------------- main kernel: one wave per sample ----------------
__global__ __launch_bounds__(256, 4) void qnn_kernel(
    const float* __restrict__ x, const float* __restrict__ Wpre,
    const float* __restrict__ bpre, const float* __restrict__ qw,
    const float* __restrict__ Wpost, const float* __restrict__ bpost,
    float* __restrict__ out)
{
  // gates: [gate][class][4] at tid*8 (tid 10..39); layer-0 raw at 320 + w*8
  __shared__ __align__(16) float Ush[400];

  const int tid = threadIdx.x;
  if (tid < 40) {
    const float phi = qw[tid * 3 + 0];
    const float th  = qw[tid * 3 + 1];
    const float om  = qw[tid * 3 + 2];
    const float c = cosf(0.5f * th), s_ = sinf(0.5f * th);
    const float A  = c;
    const float Br = -cosf(phi) * s_, Bi = -sinf(phi) * s_;
    const float Cr =  cosf(om)  * s_, Ci =  sinf(om)  * s_;
    const float Dr =  cosf(phi + om) * c, Di = sinf(phi + om) * c;
    if (tid < 10) {
      float* q = &Ush[320 + tid * 8];
      q[0] = A;  q[1] = Br; q[2] = Bi; q[3] = Cr;
      q[4] = Ci; q[5] = Dr; q[6] = Di; q[7] = 0.f;
    } else {
      float* p = &Ush[tid * 8];
      // class0 (hi=0): O=(A,0), P=(Br,Bi); class1 (hi=1): O=(Dr,Di), P=(Cr,Ci)
      p[0] = A;  p[1] = 0.f; p[2] = Br; p[3] = Bi;
      p[4] = Dr; p[5] = Di;  p[6] = Cr; p[7] = Ci;
    }
  }
  __syncthreads();

  const int lane = tid & 63;
  const int b = blockIdx.x * 4 + (tid >> 6);

  // ---- pre-net: angles = tanh(x @ Wpre^T + bpre) ----
  const float* xrow = x + (size_t)b * 128;
  const float x0 = xrow[lane];
  const float x1 = xrow[lane + 64];
  float cw[10], sw[10];
#pragma unroll
  for (int w = 0; w < 10; ++w) {
    float p = fmaf(x0, Wpre[w * 128 + lane], x1 * Wpre[w * 128 + 64 + lane]);
    p = wave_sum(p, lane);
    const float e = __expf(2.f * (p + bpre[w]));
    const float ang = 1.f - 2.f * __builtin_amdgcn_rcpf(e + 1.f);
    const float h = 0.5f * ang;
    cw[w] = __cosf(h);
    sw[w] = __sinf(h);
  }

  // ---- embedding with layer-0 fold: psi = tensor_w [Rot_w0 . (cos h, -i sin h)] ----
  float u0r[10], u0i[10], u1r[10], u1i[10];
#pragma unroll
  for (int w = 0; w < 10; ++w) {
    const float* q = &Ush[320 + w * 8];
    const float A = q[0], Br = q[1], Bi = q[2], Cr = q[3], Ci = q[4], Dr = q[5], Di = q[6];
    const float ch = cw[w], sh = sw[w];
    u0r[w] = fmaf(A, ch, Bi * sh);
    u0i[w] = -Br * sh;
    u1r[w] = fmaf(Cr, ch, Di * sh);
    u1i[w] = fmaf(Ci, ch, -Dr * sh);
  }

  // lane factor: wires 0..5 <-> lane bits 5..0
  float Lr, Li;
  {
    const int b0 = (lane >> 5) & 1;
    Lr = b0 ? u1r[0] : u0r[0];
    Li = b0 ? u1i[0] : u0i[0];
  }
#pragma unroll
  for (int w = 1; w < 6; ++w) {
    const int bb = (lane >> (5 - w)) & 1;
    const float arv = bb ? u1r[w] : u0r[w];
    const float aiv = bb ? u1i[w] : u0i[w];
    const float nr = fmaf(Lr, arv, -Li * aiv);
    const float ni = fmaf(Lr, aiv, Li * arv);
    Lr = nr; Li = ni;
  }

  // reg factors: t bits [3:2] = wires 6,7; bits [1:0] = wires 8,9
  float t4r[4], t4i[4], lsr[4], lsi[4];
#pragma unroll
  for (int a = 0; a < 2; ++a) {
#pragma unroll
    for (int c2 = 0; c2 < 2; ++c2) {
      const int k = (a << 1) | c2;
      const float ar6 = a ? u1r[6] : u0r[6], ai6 = a ? u1i[6] : u0i[6];
      const float ar7 = c2 ? u1r[7] : u0r[7], ai7 = c2 ? u1i[7] : u0i[7];
      t4r[k] = fmaf(ar6, ar7, -ai6 * ai7);
      t4i[k] = fmaf(ar6, ai7, ai6 * ar7);
      const float ar8 = a ? u1r[8] : u0r[8], ai8 = a ? u1i[8] : u0i[8];
      const float ar9 = c2 ? u1r[9] : u0r[9], ai9 = c2 ? u1i[9] : u0i[9];
      const float s4r = fmaf(ar8, ar9, -ai8 * ai9);
      const float s4i = fmaf(ar8, ai9, ai8 * ar9);
      lsr[k] = fmaf(s4r, Lr, -s4i * Li);
      lsi[k] = fmaf(s4r, Li, s4i * Lr);
    }
  }

  float ar[16], ai[16];
#pragma unroll
  for (int t = 0; t < 16; ++t) {
    const int hi4 = t >> 2, lo4 = t & 3;
    ar[t] = fmaf(t4r[hi4], lsr[lo4], -t4i[hi4] * lsi[lo4]);
    ai[t] = fmaf(t4r[hi4], lsi[lo4],  t4i[hi4] * lsr[lo4]);
  }

  // ---- layers 1..3 ----
  layer_from<1, 0>(ar, ai, Ush, lane);
  layer_from<2, 0>(ar, ai, Ush, lane);
  layer_from<3, 0>(ar, ai, Ush, lane);

  // ---- epilogue: acc = sum_p |a|^2 * g(p); g via 16-pt WHT over reg bits ----
  float Wl[10];
#pragma unroll
  for (int i = 0; i < 10; ++i) {
    const int sl = (int)(CIRC.srow[i] >> 4);
    const int par = __popc(lane & sl) & 1;
    const float wv = Wpost[i];
    Wl[i] = par ? -wv : wv;
  }
  float G[16];
#pragma unroll
  for (int m = 0; m < 16; ++m) G[m] = 0.f;
#pragma unroll
  for (int i = 0; i < 10; ++i) G[CIRC.srow[i] & 15u] += Wl[i];
#pragma unroll
  for (int bit = 1; bit < 16; bit <<= 1) {
#pragma unroll
    for (int m = 0; m < 16; ++m) {
      if (!(m & bit)) {
        const float t = G[m];
        G[m] = t + G[m ^ bit];
        G[m ^ bit] = t - G[m ^ bit];
      }
    }
  }

  float acc = 0.f;
#pragma unroll
  for (int r = 0; r < 16; ++r) {
    acc = fmaf(fmaf(ar[r], ar[r], ai[r] * ai[r]), G[r], acc);
  }
  acc = wave_sum(acc, lane);

  if (lane == 0) {
    const float z = acc + bpost[0];
    out[b] = __builtin_amdgcn_rcpf(1.f + __expf(-z));
  }
}

extern "C" void kernel_launch(void* const* d_in, const int* in_sizes, int n_in,
                              void* d_out, int out_size, void* d_ws, size_t ws_size,
                              hipStream_t stream) {
  const float* x     = (const float*)d_in[0];
  const float* Wpre  = (const float*)d_in[1];
  const float* bpre  = (const float*)d_in[2];
  const float* qw    = (const float*)d_in[3];
  const float* Wpost = (const float*)d_in[4];
  const float* bpost = (const float*)d_in[5];
  float* out = (float*)d_out;

  (void)in_sizes; (void)n_in; (void)out_size; (void)d_ws; (void)ws_size;

  qnn_kernel<<<BATCH / 4, 256, 0, stream>>>(x, Wpre, bpre, qw, Wpost, bpost, out);
}

// Round 8
// 170.423 us; speedup vs baseline: 2.9755x; 1.3762x over previous
//
#include <hip/hip_runtime.h>
#include <math.h>

#define BATCH 32768

typedef unsigned int u32;

#if defined(__has_builtin)
#if __has_builtin(__builtin_amdgcn_permlane32_swap) && __has_builtin(__builtin_amdgcn_permlane16_swap)
#define USE_PERMLANE 1
#else
#define USE_PERMLANE 0
#endif
#else
#define USE_PERMLANE 0
#endif

// ---------------------------------------------------------------------------
// Compile-time circuit derivation (lazy CNOT tracking over GF(2)).
// Physical index p (10 bits): lane = p>>4 (bits 9..4), reg t = p&15.
// One amp = one u32 = packed fp16 {re(lo), im(hi)}.
// Layer 0 folded into the embedding; layers 1..3 are generalized pair-mix
// gates with compile-time partner/select masks.
// ---------------------------------------------------------------------------
struct GateC { unsigned prt, sel; };
struct CircuitT { GateC g[4][10]; unsigned srow[10]; };

constexpr CircuitT make_circuit() {
  CircuitT C{};
  unsigned row[10], col[10];
  for (int b = 0; b < 10; ++b) { row[b] = 1u << b; col[b] = 1u << b; }
  for (int l = 0; l < 4; ++l) {
    for (int w = 0; w < 10; ++w) {
      C.g[l][w].prt = col[9 - w];
      C.g[l][w].sel = row[9 - w];
    }
    const int r = (l % 9) + 1;
    for (int w = 0; w < 10; ++w) {
      const int c = w, t = (w + r) % 10;
      const int bc = 9 - c, bt = 9 - t;
      row[bt] ^= row[bc];
      col[bc] ^= col[bt];
    }
  }
  for (int i = 0; i < 10; ++i) C.srow[i] = row[9 - i];
  return C;
}
constexpr CircuitT CIRC = make_circuit();

// ---------------- cross-lane primitives (u32) ----------------
template<int CTRL>
__device__ __forceinline__ u32 dppu(u32 v) {
  return (u32)__builtin_amdgcn_update_dpp((int)v, (int)v, CTRL, 0xF, 0xF, false);
}

template<int LOW>
__device__ __forceinline__ u32 dpp_low(u32 v) {
  static_assert(LOW >= 0 && LOW <= 15, "bad mask");
  if constexpr (LOW == 0) return v;
  else if constexpr (LOW == 1) return dppu<0xB1>(v);        // quad [1,0,3,2]
  else if constexpr (LOW == 2) return dppu<0x4E>(v);        // quad [2,3,0,1]
  else if constexpr (LOW == 3) return dppu<0x1B>(v);        // quad [3,2,1,0]
  else if constexpr (LOW == 7) return dppu<0x141>(v);       // row_half_mirror
  else if constexpr (LOW == 15) return dppu<0x140>(v);      // row_mirror
  else if constexpr (LOW >= 4 && LOW <= 6) return dpp_low<LOW ^ 7>(dppu<0x141>(v));
  else return dpp_low<LOW ^ 15>(dppu<0x140>(v));            // 8..14
}

constexpr int dpp_ops_low(int low) {
  if (low == 0) return 0;
  if (low == 1 || low == 2 || low == 3 || low == 7 || low == 15) return 1;
  if ((low >= 4 && low <= 6) || low == 8 || (low >= 12 && low <= 14)) return 2;
  return 3;
}
constexpr int chain_cost(int M) {
#if !USE_PERMLANE
  if (M & 48) return 99;
#endif
  return ((M & 32) ? 2 : 0) + ((M & 16) ? 2 : 0) + dpp_ops_low(M & 15);
}
constexpr bool use_ds_mask(int M) { return chain_cost(M) >= 2; }

#if USE_PERMLANE
__device__ __forceinline__ u32 xor16u(u32 v, int lane) {
  auto r = __builtin_amdgcn_permlane16_swap(v, v, false, false);
  return (lane & 16) ? r[0] : r[1];
}
__device__ __forceinline__ u32 xor32u(u32 v, int lane) {
  auto r = __builtin_amdgcn_permlane32_swap(v, v, false, false);
  return (lane & 32) ? r[0] : r[1];
}
#else
__device__ __forceinline__ u32 xor16u(u32 v, int lane) { return (u32)__shfl_xor((int)v, 16, 64); }
__device__ __forceinline__ u32 xor32u(u32 v, int lane) { return (u32)__shfl_xor((int)v, 32, 64); }
#endif

template<int M>
__device__ __forceinline__ u32 lshuf(u32 v, int lane, int bpa) {
  if constexpr (use_ds_mask(M)) {
    if constexpr ((M & 32) != 0) {
      return (u32)__builtin_amdgcn_ds_bpermute(bpa, (int)v);
    } else {
      return (u32)__builtin_amdgcn_ds_swizzle((int)v, 0x1F | (M << 10));
    }
  } else {
    u32 t = v;
    if constexpr ((M & 32) != 0) t = xor32u(t, lane);
    if constexpr ((M & 16) != 0) t = xor16u(t, lane);
    if constexpr ((M & 15) != 0) t = dpp_low<M & 15>(t);
    return t;
  }
}

// ---------------- float cross-lane (prenet/epilogue) ----------------
template<int CTRL>
__device__ __forceinline__ float dppf(float v) {
  const int i = __float_as_int(v);
  return __int_as_float(__builtin_amdgcn_update_dpp(i, i, CTRL, 0xF, 0xF, false));
}
__device__ __forceinline__ float shflx(float v, int m) { return __shfl_xor(v, m, 64); }

__device__ __forceinline__ float wave_sum(float v, int lane) {
  v += dppf<0xB1>(v);
  v += dppf<0x4E>(v);
  v += dppf<0x141>(v);
  v += dppf<0x140>(v);
#if USE_PERMLANE
  { auto r = __builtin_amdgcn_permlane16_swap(__float_as_uint(v), __float_as_uint(v), false, false);
    v = __uint_as_float(r[0]) + __uint_as_float(r[1]); }
  { auto r = __builtin_amdgcn_permlane32_swap(__float_as_uint(v), __float_as_uint(v), false, false);
    v = __uint_as_float(r[0]) + __uint_as_float(r[1]); }
#else
  v += shflx(v, 16);
  v += shflx(v, 32);
#endif
  return v;
}

// ---------------- packed fp16 primitives ----------------
__device__ __forceinline__ u32 pk_mul_h(u32 a, u32 b) {
  u32 d; asm("v_pk_mul_f16 %0, %1, %2" : "=v"(d) : "v"(a), "v"(b)); return d;
}
__device__ __forceinline__ u32 pk_fma_h(u32 a, u32 b, u32 c) {
  u32 d; asm("v_pk_fma_f16 %0, %1, %2, %3" : "=v"(d) : "v"(a), "v"(b), "v"(c)); return d;
}
// src0 read with halves swapped ({im,re}) — free re<->im swap for the i-terms
__device__ __forceinline__ u32 pk_fma_hsw(u32 a, u32 b, u32 c) {
  u32 d;
  asm("v_pk_fma_f16 %0, %1, %2, %3 op_sel:[1,0,0] op_sel_hi:[0,1,1]"
      : "=v"(d) : "v"(a), "v"(b), "v"(c));
  return d;
}

// pack two f32 -> fp16 pair {lo, hi}
__device__ __forceinline__ u32 pk2(float lo, float hi) {
  auto h = __builtin_amdgcn_cvt_pkrtz(lo, hi);
  return __builtin_bit_cast(u32, h);
}

// new = O*a + P*q; s = { {Or,Or}, {-Oi,Oi}, {Pr,Pr}, {-Pi,Pi} } packed fp16
__device__ __forceinline__ u32 updh(u32 a, u32 q, const uint4 s) {
  u32 t = pk_mul_h(a, s.x);
  t = pk_fma_hsw(a, s.y, t);
  t = pk_fma_h(q, s.z, t);
  t = pk_fma_hsw(q, s.w, t);
  return t;
}

template<int L, int W>
__device__ __forceinline__ void gate(u32 a[16], const u32* __restrict__ Ush, int lane) {
  constexpr unsigned PRT = CIRC.g[L][W].prt;
  constexpr unsigned SEL = CIRC.g[L][W].sel;
  constexpr int PLm = (int)(PRT >> 4), PRm = (int)(PRT & 15u);
  constexpr int SLm = (int)(SEL >> 4), SRm = (int)(SEL & 15u);

  int hl = 0;
  if constexpr (SLm != 0) hl = __popc(lane & SLm) & 1;

  // cA: coeffs for slots with class ct=0; cB: ct=1
  const u32* gb = Ush + (L * 10 + W - 10) * 8;
  const uint4 cA = *(const uint4*)(gb + (hl << 2));
  uint4 cB;
  if constexpr (SRm != 0) cB = *(const uint4*)(gb + ((hl ^ 1) << 2));
  else                    cB = cA;

  int bpa = 0;
  if constexpr (use_ds_mask(PLm) && (PLm & 32) != 0) bpa = (lane ^ PLm) << 2;

  if constexpr (PLm == 0) {
    // register-space gate
    constexpr int LB = PRm & (-PRm);
#pragma unroll
    for (int t0 = 0; t0 < 16; ++t0) {
      if (t0 & LB) continue;
      const int t1 = t0 ^ PRm;
      const uint4 s0 = (__builtin_popcount((unsigned)(t0 & SRm)) & 1) ? cB : cA;
      const uint4 s1 = (__builtin_popcount((unsigned)(t1 & SRm)) & 1) ? cB : cA;
      const u32 a0 = a[t0], a1 = a[t1];
      a[t0] = updh(a0, a1, s0);
      a[t1] = updh(a1, a0, s1);
    }
  } else if constexpr (PRm == 0) {
    // lane-crossing, same reg
#pragma unroll
    for (int t = 0; t < 16; ++t) {
      const u32 q = lshuf<PLm>(a[t], lane, bpa);
      const uint4 s = (__builtin_popcount((unsigned)(t & SRm)) & 1) ? cB : cA;
      a[t] = updh(a[t], q, s);
    }
  } else {
    // lane-crossing with reg pairing
    constexpr int LB = PRm & (-PRm);
#pragma unroll
    for (int t0 = 0; t0 < 16; ++t0) {
      if (t0 & LB) continue;
      const int t1 = t0 ^ PRm;
      const u32 q0 = lshuf<PLm>(a[t1], lane, bpa);
      const u32 q1 = lshuf<PLm>(a[t0], lane, bpa);
      const uint4 s0 = (__builtin_popcount((unsigned)(t0 & SRm)) & 1) ? cB : cA;
      const uint4 s1 = (__builtin_popcount((unsigned)(t1 & SRm)) & 1) ? cB : cA;
      a[t0] = updh(a[t0], q0, s0);
      a[t1] = updh(a[t1], q1, s1);
    }
  }
}

template<int L, int W>
__device__ __forceinline__ void layer_from(u32 a[16], const u32* __restrict__ Ush, int lane) {
  if constexpr (W < 10) {
    gate<L, W>(a, Ush, lane);
    layer_from<L, W + 1>(a, Ush, lane);
  }
}

// ---------------- main kernel: one wave per sample ----------------
__global__ __launch_bounds__(256, 4) void qnn_kernel(
    const float* __restrict__ x, const float* __restrict__ Wpre,
    const float* __restrict__ bpre, const float* __restrict__ qw,
    const float* __restrict__ Wpost, const float* __restrict__ bpost,
    float* __restrict__ out)
{
  // gates 10..39: 8 u32 each (2 classes x 4 packed coeff words) at (g-10)*8
  // layer-0 raw f32 coeffs (for embedding fold) at 240 + w*8
  __shared__ __align__(16) u32 Ush[320];

  const int tid = threadIdx.x;
  if (tid < 40) {
    const float phi = qw[tid * 3 + 0];
    const float th  = qw[tid * 3 + 1];
    const float om  = qw[tid * 3 + 2];
    const float c = cosf(0.5f * th), s_ = sinf(0.5f * th);
    const float A  = c;
    const float Br = -cosf(phi) * s_, Bi = -sinf(phi) * s_;
    const float Cr =  cosf(om)  * s_, Ci =  sinf(om)  * s_;
    const float Dr =  cosf(phi + om) * c, Di = sinf(phi + om) * c;
    if (tid < 10) {
      u32* q = &Ush[240 + tid * 8];
      q[0] = __float_as_uint(A);  q[1] = __float_as_uint(Br);
      q[2] = __float_as_uint(Bi); q[3] = __float_as_uint(Cr);
      q[4] = __float_as_uint(Ci); q[5] = __float_as_uint(Dr);
      q[6] = __float_as_uint(Di); q[7] = 0u;
    } else {
      u32* p = &Ush[(tid - 10) * 8];
      // class0 (hi=0): O=(A,0),  P=(Br,Bi)
      p[0] = pk2(A, A);   p[1] = pk2(0.f, 0.f);
      p[2] = pk2(Br, Br); p[3] = pk2(-Bi, Bi);
      // class1 (hi=1): O=(Dr,Di), P=(Cr,Ci)
      p[4] = pk2(Dr, Dr); p[5] = pk2(-Di, Di);
      p[6] = pk2(Cr, Cr); p[7] = pk2(-Ci, Ci);
    }
  }
  __syncthreads();

  const int lane = tid & 63;
  const int b = blockIdx.x * 4 + (tid >> 6);

  // ---- pre-net: angles = tanh(x @ Wpre^T + bpre) (f32) ----
  const float* xrow = x + (size_t)b * 128;
  const float x0 = xrow[lane];
  const float x1 = xrow[lane + 64];
  float cw[10], sw[10];
#pragma unroll
  for (int w = 0; w < 10; ++w) {
    float p = fmaf(x0, Wpre[w * 128 + lane], x1 * Wpre[w * 128 + 64 + lane]);
    p = wave_sum(p, lane);
    const float e = __expf(2.f * (p + bpre[w]));
    const float ang = 1.f - 2.f * __builtin_amdgcn_rcpf(e + 1.f);
    const float h = 0.5f * ang;
    cw[w] = __cosf(h);
    sw[w] = __sinf(h);
  }

  // ---- embedding with layer-0 fold (f32): psi = tensor_w [Rot_w0 . (cos h, -i sin h)] ----
  float u0r[10], u0i[10], u1r[10], u1i[10];
#pragma unroll
  for (int w = 0; w < 10; ++w) {
    const u32* q = &Ush[240 + w * 8];
    const float A = __uint_as_float(q[0]), Br = __uint_as_float(q[1]);
    const float Bi = __uint_as_float(q[2]), Cr = __uint_as_float(q[3]);
    const float Ci = __uint_as_float(q[4]), Dr = __uint_as_float(q[5]);
    const float Di = __uint_as_float(q[6]);
    const float ch = cw[w], sh = sw[w];
    u0r[w] = fmaf(A, ch, Bi * sh);
    u0i[w] = -Br * sh;
    u1r[w] = fmaf(Cr, ch, Di * sh);
    u1i[w] = fmaf(Ci, ch, -Dr * sh);
  }

  // lane factor: wires 0..5 <-> lane bits 5..0
  float Lr, Li;
  {
    const int b0 = (lane >> 5) & 1;
    Lr = b0 ? u1r[0] : u0r[0];
    Li = b0 ? u1i[0] : u0i[0];
  }
#pragma unroll
  for (int w = 1; w < 6; ++w) {
    const int bb = (lane >> (5 - w)) & 1;
    const float arv = bb ? u1r[w] : u0r[w];
    const float aiv = bb ? u1i[w] : u0i[w];
    const float nr = fmaf(Lr, arv, -Li * aiv);
    const float ni = fmaf(Lr, aiv, Li * arv);
    Lr = nr; Li = ni;
  }

  // reg factors: t bits [3:2] = wires 6,7; bits [1:0] = wires 8,9
  float t4r[4], t4i[4], lsr[4], lsi[4];
#pragma unroll
  for (int aa = 0; aa < 2; ++aa) {
#pragma unroll
    for (int c2 = 0; c2 < 2; ++c2) {
      const int k = (aa << 1) | c2;
      const float ar6 = aa ? u1r[6] : u0r[6], ai6 = aa ? u1i[6] : u0i[6];
      const float ar7 = c2 ? u1r[7] : u0r[7], ai7 = c2 ? u1i[7] : u0i[7];
      t4r[k] = fmaf(ar6, ar7, -ai6 * ai7);
      t4i[k] = fmaf(ar6, ai7, ai6 * ar7);
      const float ar8 = aa ? u1r[8] : u0r[8], ai8 = aa ? u1i[8] : u0i[8];
      const float ar9 = c2 ? u1r[9] : u0r[9], ai9 = c2 ? u1i[9] : u0i[9];
      const float s4r = fmaf(ar8, ar9, -ai8 * ai9);
      const float s4i = fmaf(ar8, ai9, ai8 * ar9);
      lsr[k] = fmaf(s4r, Lr, -s4i * Li);
      lsi[k] = fmaf(s4r, Li, s4i * Lr);
    }
  }

  // state: 16 packed fp16 {re,im} amps
  u32 a[16];
#pragma unroll
  for (int t = 0; t < 16; ++t) {
    const int hi4 = t >> 2, lo4 = t & 3;
    const float re = fmaf(t4r[hi4], lsr[lo4], -t4i[hi4] * lsi[lo4]);
    const float im = fmaf(t4r[hi4], lsi[lo4],  t4i[hi4] * lsr[lo4]);
    a[t] = pk2(re, im);
  }

  // ---- layers 1..3 in packed fp16 ----
  layer_from<1, 0>(a, Ush, lane);
  layer_from<2, 0>(a, Ush, lane);
  layer_from<3, 0>(a, Ush, lane);

  // ---- epilogue (f32): acc = sum_p |a|^2 * g(p); g via 16-pt WHT over reg bits ----
  float Wl[10];
#pragma unroll
  for (int i = 0; i < 10; ++i) {
    const int sl = (int)(CIRC.srow[i] >> 4);
    const int par = __popc(lane & sl) & 1;
    const float wv = Wpost[i];
    Wl[i] = par ? -wv : wv;
  }
  float G[16];
#pragma unroll
  for (int m = 0; m < 16; ++m) G[m] = 0.f;
#pragma unroll
  for (int i = 0; i < 10; ++i) G[CIRC.srow[i] & 15u] += Wl[i];
#pragma unroll
  for (int bit = 1; bit < 16; bit <<= 1) {
#pragma unroll
    for (int m = 0; m < 16; ++m) {
      if (!(m & bit)) {
        const float t = G[m];
        G[m] = t + G[m ^ bit];
        G[m ^ bit] = t - G[m ^ bit];
      }
    }
  }

  union H2U { u32 u; _Float16 h[2]; };
  float acc = 0.f;
#pragma unroll
  for (int t = 0; t < 16; ++t) {
    H2U z; z.u = a[t];
    const float rr = (float)z.h[0];
    const float ii = (float)z.h[1];
    acc = fmaf(fmaf(rr, rr, ii * ii), G[t], acc);
  }
  acc = wave_sum(acc, lane);

  if (lane == 0) {
    const float z = acc + bpost[0];
    out[b] = __builtin_amdgcn_rcpf(1.f + __expf(-z));
  }
}

extern "C" void kernel_launch(void* const* d_in, const int* in_sizes, int n_in,
                              void* d_out, int out_size, void* d_ws, size_t ws_size,
                              hipStream_t stream) {
  const float* x     = (const float*)d_in[0];
  const float* Wpre  = (const float*)d_in[1];
  const float* bpre  = (const float*)d_in[2];
  const float* qw    = (const float*)d_in[3];
  const float* Wpost = (const float*)d_in[4];
  const float* bpost = (const float*)d_in[5];
  float* out = (float*)d_out;

  (void)in_sizes; (void)n_in; (void)out_size; (void)d_ws; (void)ws_size;

  qnn_kernel<<<BATCH / 4, 256, 0, stream>>>(x, Wpre, bpre, qw, Wpost, bpost, out);
}